// Round 5
// baseline (883.985 us; speedup 1.0000x reference)
//
#include <hip/hip_runtime.h>
#include <hip/hip_bf16.h>
#include <math.h>

#define NTOK 8192
#define DIM 256
#define KCB 4096
#define NCB (KCB / 128)   // 32 col-blocks in score GEMM
#define NKEY 4            // top-4 kept per (row, col-block)
#define DELTA 0.08f       // candidate window, raw-dot units (>20 sigma of bf16 GEMM noise)
#define MAXC 16

typedef unsigned long long ull;
typedef unsigned short ushort;
typedef __attribute__((ext_vector_type(8))) short shortx8;   // 8 bf16 (4 VGPRs)
typedef __attribute__((ext_vector_type(4))) float floatx4;

// ---- float <-> order-preserving u32 ----
__device__ __forceinline__ unsigned f2ord(float f) {
    unsigned u = __float_as_uint(f);
    return (u & 0x80000000u) ? ~u : (u | 0x80000000u);
}
__device__ __forceinline__ float ord2f(unsigned u) {
    unsigned b = (u & 0x80000000u) ? (u & 0x7FFFFFFFu) : ~u;
    return __uint_as_float(b);
}
__device__ __forceinline__ ushort f2bf(float f) {   // RNE fp32->bf16
    unsigned u = __float_as_uint(f);
    unsigned r = u + 0x7FFFu + ((u >> 16) & 1u);
    return (ushort)(r >> 16);
}
// insert v into descending sorted top-4 (a0>=a1>=a2>=a3)
__device__ __forceinline__ void ins4(ull v, ull& a0, ull& a1, ull& a2, ull& a3) {
    if (v > a3) {
        if (v > a2) {
            a3 = a2;
            if (v > a1) { a2 = a1; if (v > a0) { a1 = a0; a0 = v; } else a1 = v; }
            else a2 = v;
        } else a3 = v;
    }
}

// ---- numpy float32 pairwise-sum norm over 256 contiguous elements ----
__device__ float np_norm256(const float* __restrict__ a) {
    float half[2];
#pragma unroll 1
    for (int h = 0; h < 2; ++h) {
        const float* p = a + h * 128;
        float r[8];
#pragma unroll
        for (int j = 0; j < 8; ++j) r[j] = __fmul_rn(p[j], p[j]);
#pragma unroll 1
        for (int i = 8; i < 128; i += 8)
#pragma unroll
            for (int j = 0; j < 8; ++j)
                r[j] = __fadd_rn(r[j], __fmul_rn(p[i + j], p[i + j]));
        float t0 = __fadd_rn(r[0], r[1]);
        float t1 = __fadd_rn(r[2], r[3]);
        float t2 = __fadd_rn(r[4], r[5]);
        float t3 = __fadd_rn(r[6], r[7]);
        half[h] = __fadd_rn(__fadd_rn(t0, t1), __fadd_rn(t2, t3));
    }
    float s = __fadd_rn(half[0], half[1]);
    return fmaxf(sqrtf(s), 1e-12f);
}

// ---- init accumulators ----
__global__ void init_ws(unsigned* counts, float* scal, unsigned* pmin) {
    int i = blockIdx.x * blockDim.x + threadIdx.x;
    if (i < KCB) counts[i] = 0u;
    if (i == 0) { scal[0] = 0.f; scal[1] = 0.f; scal[2] = 0.f; pmin[0] = 0xFFFFFFFFu; }
}

// ---- per-row np-emulated fp32 norms ----
__global__ void np_norms(const float* __restrict__ src, float* __restrict__ nrm, int nrows) {
    int r = blockIdx.x * blockDim.x + threadIdx.x;
    if (r < nrows) nrm[r] = np_norm256(src + (size_t)r * DIM);
}

// ---- latent fp32 -> bf16 ----
__global__ void lat2bf(const float* __restrict__ lat, ushort* __restrict__ latbf) {
    int i = blockIdx.x * blockDim.x + threadIdx.x;
    latbf[i] = f2bf(lat[i]);
}

// ---- codebook: cnbf = bf16(c/nrmc), cbbf = bf16(c), sq = fp32(fp64 sumsq) ----
__global__ void cb_apply(const float* __restrict__ cb, const float* __restrict__ nrmc,
                         ushort* __restrict__ cnbf, ushort* __restrict__ cbbf,
                         float* __restrict__ sq) {
    int n = blockIdx.x, t = threadIdx.x;
    float c = cb[n * DIM + t];
    cnbf[n * DIM + t] = f2bf(c / nrmc[n]);
    cbbf[n * DIM + t] = f2bf(c);
    __shared__ double red[256];
    red[t] = (double)c * (double)c; __syncthreads();
    for (int s = 128; s > 0; s >>= 1) { if (t < s) red[t] += red[t + s]; __syncthreads(); }
    if (t == 0) sq[n] = (float)red[0];
}

// ---- bf16 MFMA score GEMM (latbf x cnbf^T) + per-row top-4 per 128-col block ----
// 128x128 tile, 4 waves, each wave 32 rows x 128 cols (2 mt x 8 nt of 16x16x32).
__global__ __launch_bounds__(256) void scores_mfma(const ushort* __restrict__ A,
                                                   const ushort* __restrict__ B,
                                                   ull* __restrict__ keysw) {
    __shared__ ushort As[128][40];   // +8 pad: 80 B row stride, ~2-way banks
    __shared__ ushort Bs[128][40];
    int tid = threadIdx.x;
    int wave = tid >> 6, lane = tid & 63;
    int quad = lane >> 4, l15 = lane & 15;
    int rowBase = blockIdx.y * 128, colBase = blockIdx.x * 128;
    int wrow = wave * 32;
    floatx4 acc[2][8];
#pragma unroll
    for (int m = 0; m < 2; ++m)
#pragma unroll
        for (int n = 0; n < 8; ++n) acc[m][n] = (floatx4){0.f, 0.f, 0.f, 0.f};
    int srow = tid >> 1, shalf = tid & 1;
    const ushort* gA = A + (size_t)(rowBase + srow) * DIM + shalf * 16;
    const ushort* gB = B + (size_t)(colBase + srow) * DIM + shalf * 16;
    for (int kk = 0; kk < DIM; kk += 32) {
        uint4 av0 = *(const uint4*)(gA + kk);
        uint4 av1 = *(const uint4*)(gA + kk + 8);
        uint4 bv0 = *(const uint4*)(gB + kk);
        uint4 bv1 = *(const uint4*)(gB + kk + 8);
        __syncthreads();
        *(uint4*)&As[srow][shalf * 16] = av0;
        *(uint4*)&As[srow][shalf * 16 + 8] = av1;
        *(uint4*)&Bs[srow][shalf * 16] = bv0;
        *(uint4*)&Bs[srow][shalf * 16 + 8] = bv1;
        __syncthreads();
        shortx8 afrag[2], bfrag[8];
#pragma unroll
        for (int mt = 0; mt < 2; ++mt)
            afrag[mt] = *(const shortx8*)&As[wrow + mt * 16 + l15][quad * 8];
#pragma unroll
        for (int nt = 0; nt < 8; ++nt)
            bfrag[nt] = *(const shortx8*)&Bs[nt * 16 + l15][quad * 8];
#pragma unroll
        for (int mt = 0; mt < 2; ++mt)
#pragma unroll
            for (int nt = 0; nt < 8; ++nt)
                acc[mt][nt] = __builtin_amdgcn_mfma_f32_16x16x32_bf16(
                    afrag[mt], bfrag[nt], acc[mt][nt], 0, 0, 0);
    }
    // epilogue: per row-slot top-4 of this wave's 128 cols, in-quad butterfly
#pragma unroll
    for (int mt = 0; mt < 2; ++mt)
#pragma unroll
        for (int reg = 0; reg < 4; ++reg) {
            ull a0 = 0, a1 = 0, a2 = 0, a3 = 0;
#pragma unroll
            for (int nt = 0; nt < 8; ++nt) {
                unsigned col = (unsigned)(colBase + nt * 16 + l15);
                ull key = ((ull)f2ord(acc[mt][nt][reg]) << 32) |
                          (ull)(0xFFFFFFFFu - col);
                ins4(key, a0, a1, a2, a3);
            }
#pragma unroll
            for (int m = 1; m < 16; m <<= 1) {
                ull r0 = __shfl_xor(a0, m, 64);
                ull r1 = __shfl_xor(a1, m, 64);
                ull r2 = __shfl_xor(a2, m, 64);
                ull r3 = __shfl_xor(a3, m, 64);
                ins4(r0, a0, a1, a2, a3); ins4(r1, a0, a1, a2, a3);
                ins4(r2, a0, a1, a2, a3); ins4(r3, a0, a1, a2, a3);
            }
            if (l15 == 0) {
                int row = rowBase + wrow + mt * 16 + quad * 4 + reg;
                size_t base = (size_t)(blockIdx.x * NKEY) * NTOK + row;
                keysw[base] = a0;
                keysw[base + NTOK] = a1;
                keysw[base + 2 * NTOK] = a2;
                keysw[base + 3 * NTOK] = a3;
            }
        }
}

// ---- bf16 MFMA codebook pairwise: upper-triangle tiles, fused sum/min ----
__global__ __launch_bounds__(256) void pairwise_mfma(const ushort* __restrict__ C,
                                                     const float* __restrict__ sq,
                                                     float* __restrict__ pairSum,
                                                     unsigned* __restrict__ pairMin) {
    if (blockIdx.y > blockIdx.x) return;
    __shared__ ushort As[128][40];
    __shared__ ushort Bs[128][40];
    __shared__ float rs[256], rm[256];
    int tid = threadIdx.x;
    int wave = tid >> 6, lane = tid & 63;
    int quad = lane >> 4, l15 = lane & 15;
    int rowBase = blockIdx.y * 128, colBase = blockIdx.x * 128;
    int wrow = wave * 32;
    floatx4 acc[2][8];
#pragma unroll
    for (int m = 0; m < 2; ++m)
#pragma unroll
        for (int n = 0; n < 8; ++n) acc[m][n] = (floatx4){0.f, 0.f, 0.f, 0.f};
    int srow = tid >> 1, shalf = tid & 1;
    const ushort* gA = C + (size_t)(rowBase + srow) * DIM + shalf * 16;
    const ushort* gB = C + (size_t)(colBase + srow) * DIM + shalf * 16;
    for (int kk = 0; kk < DIM; kk += 32) {
        uint4 av0 = *(const uint4*)(gA + kk);
        uint4 av1 = *(const uint4*)(gA + kk + 8);
        uint4 bv0 = *(const uint4*)(gB + kk);
        uint4 bv1 = *(const uint4*)(gB + kk + 8);
        __syncthreads();
        *(uint4*)&As[srow][shalf * 16] = av0;
        *(uint4*)&As[srow][shalf * 16 + 8] = av1;
        *(uint4*)&Bs[srow][shalf * 16] = bv0;
        *(uint4*)&Bs[srow][shalf * 16 + 8] = bv1;
        __syncthreads();
        shortx8 afrag[2], bfrag[8];
#pragma unroll
        for (int mt = 0; mt < 2; ++mt)
            afrag[mt] = *(const shortx8*)&As[wrow + mt * 16 + l15][quad * 8];
#pragma unroll
        for (int nt = 0; nt < 8; ++nt)
            bfrag[nt] = *(const shortx8*)&Bs[nt * 16 + l15][quad * 8];
#pragma unroll
        for (int mt = 0; mt < 2; ++mt)
#pragma unroll
            for (int nt = 0; nt < 8; ++nt)
                acc[mt][nt] = __builtin_amdgcn_mfma_f32_16x16x32_bf16(
                    afrag[mt], bfrag[nt], acc[mt][nt], 0, 0, 0);
    }
    float lsum = 0.f, lmin = INFINITY;
#pragma unroll
    for (int mt = 0; mt < 2; ++mt)
#pragma unroll
        for (int reg = 0; reg < 4; ++reg) {
            int i = rowBase + wrow + mt * 16 + quad * 4 + reg;
            float sqi = sq[i];
#pragma unroll
            for (int nt = 0; nt < 8; ++nt) {
                int j = colBase + nt * 16 + l15;
                if (i < j) {
                    float d2 = sqi + sq[j] - 2.0f * acc[mt][nt][reg];
                    float d = sqrtf(fmaxf(d2, 0.0f));
                    lsum += d;
                    lmin = fminf(lmin, d);
                }
            }
        }
    rs[tid] = lsum; rm[tid] = lmin; __syncthreads();
    for (int s = 128; s > 0; s >>= 1) {
        if (tid < s) { rs[tid] += rs[tid + s]; rm[tid] = fminf(rm[tid], rm[tid + s]); }
        __syncthreads();
    }
    if (tid == 0) { atomicAdd(pairSum, rs[0]); atomicMin(pairMin, f2ord(rm[0])); }
}

// ---- per-row: bit-emulate the reference's fp32 pipeline on candidates ----
__global__ __launch_bounds__(256) void argmax_resolve(const float* __restrict__ lat,
                                                      const float* __restrict__ cb,
                                                      const float* __restrict__ nrml,
                                                      const float* __restrict__ nrmc,
                                                      const ull* __restrict__ keysw,
                                                      float* __restrict__ outidx,
                                                      int* __restrict__ fidx,
                                                      unsigned* __restrict__ counts,
                                                      float* __restrict__ scal) {
    int n = blockIdx.x * 256 + threadIdx.x;
    ull k1 = 0ull;
    for (int j = 0; j < NKEY * NCB; ++j) {
        ull v = keysw[(size_t)j * NTOK + n];
        if (v > k1) k1 = v;
    }
    float v1 = ord2f((unsigned)(k1 >> 32));
    float thresh = v1 - DELTA;
    int cand[MAXC]; int nc = 0;
    for (int j = 0; j < NKEY * NCB; ++j) {
        ull v = keysw[(size_t)j * NTOK + n];
        float val = ord2f((unsigned)(v >> 32));
        if (val >= thresh && nc < MAXC)
            cand[nc++] = (int)(0xFFFFFFFFu - (unsigned)(v & 0xFFFFFFFFull));
    }
    // sort candidates ascending
    for (int a = 1; a < nc; ++a) {
        int key = cand[a]; int b = a - 1;
        while (b >= 0 && cand[b] > key) { cand[b + 1] = cand[b]; --b; }
        cand[b + 1] = key;
    }
    float nx = nrml[n];
    const float* x = lat + (size_t)n * DIM;
    float bestf = INFINITY, bestm = INFINITY, caf[MAXC];
    int bif = 0x7FFFFFFF, bim = 0x7FFFFFFF;
    for (int c = 0; c < nc; ++c) {
        int k = cand[c];
        const float* cr = cb + (size_t)k * DIM;
        float nk = nrmc[k];
        float af = 0.f, am = 0.f;
        for (int d = 0; d < DIM; ++d) {
            float la = x[d] / nx;       // IEEE fp32 divide
            float cv = cr[d] / nk;
            af = fmaf(la, cv, af);                  // FMA chain
            am = __fadd_rn(am, __fmul_rn(la, cv));  // mul+add chain
        }
        float df = __fsub_rn(2.0f, __fmul_rn(2.0f, af));
        float dm = __fsub_rn(2.0f, __fmul_rn(2.0f, am));
        caf[c] = af;
        if (df < bestf) { bestf = df; bif = k; }
        if (dm < bestm) { bestm = dm; bim = k; }
    }
    int idx = (bif == bim) ? bif : (bif < bim ? bif : bim);
    float selcos = 0.f;
    for (int c = 0; c < nc; ++c) if (cand[c] == idx) selcos = caf[c];
    fidx[n] = idx;
    outidx[n] = (float)idx;
    atomicAdd(&counts[idx], 1u);
    __shared__ float red[256];
    red[threadIdx.x] = selcos; __syncthreads();
    for (int s = 128; s > 0; s >>= 1) {
        if (threadIdx.x < s) red[threadIdx.x] += red[threadIdx.x + s];
        __syncthreads();
    }
    if (threadIdx.x == 0) atomicAdd(&scal[1], red[0]);
}

// ---- gather quantized + mse (16 rows per block) ----
__global__ __launch_bounds__(256) void gather_out(const float* __restrict__ latent,
                                                  const float* __restrict__ codebook,
                                                  const int* __restrict__ fidx,
                                                  float* __restrict__ outq,
                                                  float* __restrict__ scal) {
    int t = threadIdx.x;
    int n0 = blockIdx.x * 16;
    float msePart = 0.f;
    for (int r = 0; r < 16; ++r) {
        int n = n0 + r;
        int idx = fidx[n];
        float q = codebook[(size_t)idx * DIM + t];
        float x = latent[(size_t)n * DIM + t];
        outq[(size_t)n * DIM + t] = q;
        float d = x - q;
        msePart = fmaf(d, d, msePart);
    }
    __shared__ float red[256];
    red[t] = msePart; __syncthreads();
    for (int s = 128; s > 0; s >>= 1) { if (t < s) red[t] += red[t + s]; __syncthreads(); }
    if (t == 0) atomicAdd(&scal[0], red[0]);
}

// ---- scalars ----
__global__ void finalize(const unsigned* __restrict__ counts, const float* __restrict__ scal,
                         const unsigned* __restrict__ pmin, float* __restrict__ outs) {
    int t = threadIdx.x;
    float h = 0.f;
    for (int k = t; k < KCB; k += 256) {
        float p = (float)counts[k] * (1.0f / (float)NTOK);
        h += p * logf(p + 1e-10f);
    }
    __shared__ float red[256];
    red[t] = h; __syncthreads();
    for (int s = 128; s > 0; s >>= 1) { if (t < s) red[t] += red[t + s]; __syncthreads(); }
    if (t == 0) {
        float mse = scal[0] / (float)(NTOK * DIM);
        outs[0] = 0.25f * mse;
        outs[1] = mse;
        outs[2] = expf(-red[0]);
        outs[3] = scal[1] / (float)NTOK;
        outs[4] = scal[2] * 2.0f / ((float)KCB * (float)(KCB - 1));
        outs[5] = ord2f(pmin[0]);
    }
}

extern "C" void kernel_launch(void* const* d_in, const int* in_sizes, int n_in,
                              void* d_out, int out_size, void* d_ws, size_t ws_size,
                              hipStream_t stream) {
    const float* latent = (const float*)d_in[0];    // [8192,256]
    const float* codebook = (const float*)d_in[1];  // [4096,256]
    float* out = (float*)d_out;
    float* outq = out;
    float* outidx = out + (size_t)NTOK * DIM;
    float* outs = outidx + NTOK;

    ull* keysw = (ull*)d_ws;                              // 128*8192 u64 = 8 MB
    ushort* latbf = (ushort*)(keysw + NKEY * NCB * NTOK); // 4 MB
    ushort* cnbf = latbf + (size_t)NTOK * DIM;            // 2 MB
    ushort* cbbf = cnbf + (size_t)KCB * DIM;              // 2 MB
    float* nrml = (float*)(cbbf + (size_t)KCB * DIM);     // 8192
    float* nrmc = nrml + NTOK;                            // 4096
    float* sq = nrmc + KCB;                               // 4096
    int* fidx = (int*)(sq + KCB);                         // 8192
    unsigned* counts = (unsigned*)(fidx + NTOK);          // 4096
    float* scal = (float*)(counts + KCB);                 // [mse, sel, pairsum]
    unsigned* pmin = (unsigned*)(scal + 3);

    hipLaunchKernelGGL(init_ws, dim3((KCB + 255) / 256), dim3(256), 0, stream, counts, scal, pmin);
    hipLaunchKernelGGL(np_norms, dim3(NTOK / 256), dim3(256), 0, stream, latent, nrml, NTOK);
    hipLaunchKernelGGL(np_norms, dim3(KCB / 256), dim3(256), 0, stream, codebook, nrmc, KCB);
    hipLaunchKernelGGL(lat2bf, dim3(NTOK * DIM / 256), dim3(256), 0, stream, latent, latbf);
    hipLaunchKernelGGL(cb_apply, dim3(KCB), dim3(256), 0, stream, codebook, nrmc, cnbf, cbbf, sq);
    hipLaunchKernelGGL(scores_mfma, dim3(NCB, NTOK / 128), dim3(256), 0, stream, latbf, cnbf, keysw);
    hipLaunchKernelGGL(argmax_resolve, dim3(NTOK / 256), dim3(256), 0, stream,
                       latent, codebook, nrml, nrmc, keysw, outidx, fidx, counts, scal);
    hipLaunchKernelGGL(pairwise_mfma, dim3(KCB / 128, KCB / 128), dim3(256), 0, stream, cbbf, sq,
                       &scal[2], pmin);
    hipLaunchKernelGGL(gather_out, dim3(NTOK / 16), dim3(256), 0, stream, latent, codebook, fidx,
                       outq, scal);
    hipLaunchKernelGGL(finalize, dim3(1), dim3(256), 0, stream, counts, scal, pmin, outs);
}

// Round 6
// 410.555 us; speedup vs baseline: 2.1531x; 2.1531x over previous
//
#include <hip/hip_runtime.h>
#include <hip/hip_bf16.h>
#include <math.h>

#define NTOK 8192
#define DIM 256
#define KCB 4096
#define NCB (KCB / 128)   // 32 col-blocks in score GEMM
#define NKEY 4            // top-4 kept per (row, col-block)
#define DELTA 0.08f       // candidate window, raw-dot units (>20 sigma of bf16 noise)
#define MAXC 16

typedef unsigned long long ull;
typedef unsigned short ushort;
typedef __attribute__((ext_vector_type(8))) short shortx8;   // 8 bf16 (4 VGPRs)
typedef __attribute__((ext_vector_type(4))) float floatx4;
typedef const __attribute__((address_space(1))) void* gas_cp;
typedef __attribute__((address_space(3))) void* las_p;

// ---- float <-> order-preserving u32 ----
__device__ __forceinline__ unsigned f2ord(float f) {
    unsigned u = __float_as_uint(f);
    return (u & 0x80000000u) ? ~u : (u | 0x80000000u);
}
__device__ __forceinline__ float ord2f(unsigned u) {
    unsigned b = (u & 0x80000000u) ? (u & 0x7FFFFFFFu) : ~u;
    return __uint_as_float(b);
}
__device__ __forceinline__ ushort f2bf(float f) {   // RNE fp32->bf16
    unsigned u = __float_as_uint(f);
    unsigned r = u + 0x7FFFu + ((u >> 16) & 1u);
    return (ushort)(r >> 16);
}

// ---- shared-memory union: GEMM tiles alias the epilogue key store ----
union TileSmem {
    struct { ushort a[128][64]; ushort b[128][64]; } t;   // 32 KB
    ull keys[128][33];                                    // 33 KB (+pad col)
};

// ---- async stage: 128 rows x 64 ushorts, XOR-swizzled chunks, 4 calls/wave ----
// global_load_lds writes lane i at ldsbase + i*16 (wave-uniform base, m104);
// lane i covers (row j*8 + i>>3, phys chunk i&7); it FETCHES logical chunk
// (i&7)^((i>>3)&7) so that logical chunk lc of row r lives at phys lc^(r&7).
__device__ __forceinline__ void stage_tile(const ushort* __restrict__ gbase,
                                           ushort (*lds)[64], int wave, int lane,
                                           int kk) {
    int p = lane & 7;
    int rsub = lane >> 3;
    int kc = p ^ (rsub & 7);
#pragma unroll
    for (int c = 0; c < 4; ++c) {
        int j = wave * 4 + c;
        const ushort* src = gbase + (size_t)(j * 8 + rsub) * DIM + kk + kc * 8;
        __builtin_amdgcn_global_load_lds((gas_cp)src, (las_p)&lds[j * 8][0], 16, 0, 0);
    }
}
__device__ __forceinline__ shortx8 frag_read(const ushort (*lds)[64], int row,
                                             int lc) {
    return *(const shortx8*)&lds[row][(lc ^ (row & 7)) * 8];
}

// ---- numpy float32 pairwise-sum norm over 256 contiguous elements ----
__device__ float np_norm256(const float* __restrict__ a) {
    float half[2];
#pragma unroll 1
    for (int h = 0; h < 2; ++h) {
        const float* p = a + h * 128;
        float r[8];
#pragma unroll
        for (int j = 0; j < 8; ++j) r[j] = __fmul_rn(p[j], p[j]);
#pragma unroll 1
        for (int i = 8; i < 128; i += 8)
#pragma unroll
            for (int j = 0; j < 8; ++j)
                r[j] = __fadd_rn(r[j], __fmul_rn(p[i + j], p[i + j]));
        float t0 = __fadd_rn(r[0], r[1]);
        float t1 = __fadd_rn(r[2], r[3]);
        float t2 = __fadd_rn(r[4], r[5]);
        float t3 = __fadd_rn(r[6], r[7]);
        half[h] = __fadd_rn(__fadd_rn(t0, t1), __fadd_rn(t2, t3));
    }
    float s = __fadd_rn(half[0], half[1]);
    return fmaxf(sqrtf(s), 1e-12f);
}

// ---- init accumulators ----
__global__ void init_ws(unsigned* counts, float* scal, unsigned* pmin) {
    int i = blockIdx.x * blockDim.x + threadIdx.x;
    if (i < KCB) counts[i] = 0u;
    if (i == 0) { scal[0] = 0.f; scal[1] = 0.f; scal[2] = 0.f; pmin[0] = 0xFFFFFFFFu; }
}

__global__ void np_norms(const float* __restrict__ src, float* __restrict__ nrm, int nrows) {
    int r = blockIdx.x * blockDim.x + threadIdx.x;
    if (r < nrows) nrm[r] = np_norm256(src + (size_t)r * DIM);
}

__global__ void lat2bf(const float* __restrict__ lat, ushort* __restrict__ latbf) {
    int i = blockIdx.x * blockDim.x + threadIdx.x;
    latbf[i] = f2bf(lat[i]);
}

__global__ void cb_apply(const float* __restrict__ cb, const float* __restrict__ nrmc,
                         ushort* __restrict__ cnbf, ushort* __restrict__ cbbf,
                         float* __restrict__ sq) {
    int n = blockIdx.x, t = threadIdx.x;
    float c = cb[n * DIM + t];
    cnbf[n * DIM + t] = f2bf(c / nrmc[n]);
    cbbf[n * DIM + t] = f2bf(c);
    __shared__ double red[256];
    red[t] = (double)c * (double)c; __syncthreads();
    for (int s = 128; s > 0; s >>= 1) { if (t < s) red[t] += red[t + s]; __syncthreads(); }
    if (t == 0) sq[n] = (float)red[0];
}

// ---- bf16 MFMA score GEMM + branchless per-row top-4 per 128-col block ----
// 128x128 tile, 4 waves x (32 rows x 128 cols), BK=64, global_load_lds staging.
__global__ __launch_bounds__(256) void scores_mfma(const ushort* __restrict__ A,
                                                   const ushort* __restrict__ B,
                                                   ull* __restrict__ keysw) {
    __shared__ TileSmem sm;
    int tid = threadIdx.x;
    int wave = tid >> 6, lane = tid & 63;
    int quad = lane >> 4, l15 = lane & 15;
    int rowBase = blockIdx.y * 128, colBase = blockIdx.x * 128;
    int wrow = wave * 32;
    floatx4 acc[2][8];
#pragma unroll
    for (int m = 0; m < 2; ++m)
#pragma unroll
        for (int n = 0; n < 8; ++n) acc[m][n] = (floatx4){0.f, 0.f, 0.f, 0.f};
    const ushort* gA = A + (size_t)rowBase * DIM;
    const ushort* gB = B + (size_t)colBase * DIM;
#pragma unroll 1
    for (int kk = 0; kk < DIM; kk += 64) {
        __syncthreads();
        stage_tile(gA, sm.t.a, wave, lane, kk);
        stage_tile(gB, sm.t.b, wave, lane, kk);
        __syncthreads();
#pragma unroll
        for (int s = 0; s < 2; ++s) {
            shortx8 af[2], bf[8];
#pragma unroll
            for (int mt = 0; mt < 2; ++mt)
                af[mt] = frag_read(sm.t.a, wrow + mt * 16 + l15, s * 4 + quad);
#pragma unroll
            for (int nt = 0; nt < 8; ++nt)
                bf[nt] = frag_read(sm.t.b, nt * 16 + l15, s * 4 + quad);
#pragma unroll
            for (int mt = 0; mt < 2; ++mt)
#pragma unroll
                for (int nt = 0; nt < 8; ++nt)
                    acc[mt][nt] = __builtin_amdgcn_mfma_f32_16x16x32_bf16(
                        af[mt], bf[nt], acc[mt][nt], 0, 0, 0);
        }
    }
    __syncthreads();   // tiles dead; reuse LDS as keys
    // branchless per-lane top-2 over nt, spill to LDS
#pragma unroll
    for (int mt = 0; mt < 2; ++mt)
#pragma unroll
        for (int reg = 0; reg < 4; ++reg) {
            ull b1 = 0ull, b2 = 0ull;
#pragma unroll
            for (int nt = 0; nt < 8; ++nt) {
                unsigned col = (unsigned)(colBase + nt * 16 + l15);
                ull key = ((ull)f2ord(acc[mt][nt][reg]) << 32) |
                          (ull)(0xFFFFFFFFu - col);
                ull lo = key < b1 ? key : b1;
                b1 = key > b1 ? key : b1;
                b2 = lo > b2 ? lo : b2;
            }
            int row = wrow + mt * 16 + quad * 4 + reg;
            sm.keys[row][l15 * 2] = b1;
            sm.keys[row][l15 * 2 + 1] = b2;
        }
    __syncthreads();
    if (tid < 128) {
        ull a0 = 0, a1 = 0, a2 = 0, a3 = 0;
#pragma unroll
        for (int j = 0; j < 32; ++j) {
            ull v = sm.keys[tid][j];
            ull n0 = v < a0 ? v : a0; a0 = v > a0 ? v : a0;
            ull n1 = n0 < a1 ? n0 : a1; a1 = n0 > a1 ? n0 : a1;
            ull n2 = n1 < a2 ? n1 : a2; a2 = n1 > a2 ? n1 : a2;
            a3 = n2 > a3 ? n2 : a3;
        }
        size_t base = (size_t)(blockIdx.x * NKEY) * NTOK + rowBase + tid;
        keysw[base] = a0;
        keysw[base + NTOK] = a1;
        keysw[base + 2 * NTOK] = a2;
        keysw[base + 3 * NTOK] = a3;
    }
}

// ---- bf16 MFMA codebook pairwise: upper-triangle tiles, fused sum/min ----
__global__ __launch_bounds__(256) void pairwise_mfma(const ushort* __restrict__ C,
                                                     const float* __restrict__ sq,
                                                     float* __restrict__ pairSum,
                                                     unsigned* __restrict__ pairMin) {
    if (blockIdx.y > blockIdx.x) return;
    __shared__ TileSmem sm;
    __shared__ float rs[256], rm[256];
    int tid = threadIdx.x;
    int wave = tid >> 6, lane = tid & 63;
    int quad = lane >> 4, l15 = lane & 15;
    int rowBase = blockIdx.y * 128, colBase = blockIdx.x * 128;
    int wrow = wave * 32;
    floatx4 acc[2][8];
#pragma unroll
    for (int m = 0; m < 2; ++m)
#pragma unroll
        for (int n = 0; n < 8; ++n) acc[m][n] = (floatx4){0.f, 0.f, 0.f, 0.f};
    const ushort* gA = C + (size_t)rowBase * DIM;
    const ushort* gB = C + (size_t)colBase * DIM;
#pragma unroll 1
    for (int kk = 0; kk < DIM; kk += 64) {
        __syncthreads();
        stage_tile(gA, sm.t.a, wave, lane, kk);
        stage_tile(gB, sm.t.b, wave, lane, kk);
        __syncthreads();
#pragma unroll
        for (int s = 0; s < 2; ++s) {
            shortx8 af[2], bf[8];
#pragma unroll
            for (int mt = 0; mt < 2; ++mt)
                af[mt] = frag_read(sm.t.a, wrow + mt * 16 + l15, s * 4 + quad);
#pragma unroll
            for (int nt = 0; nt < 8; ++nt)
                bf[nt] = frag_read(sm.t.b, nt * 16 + l15, s * 4 + quad);
#pragma unroll
            for (int mt = 0; mt < 2; ++mt)
#pragma unroll
                for (int nt = 0; nt < 8; ++nt)
                    acc[mt][nt] = __builtin_amdgcn_mfma_f32_16x16x32_bf16(
                        af[mt], bf[nt], acc[mt][nt], 0, 0, 0);
        }
    }
    float lsum = 0.f, lmin = INFINITY;
#pragma unroll
    for (int mt = 0; mt < 2; ++mt)
#pragma unroll
        for (int reg = 0; reg < 4; ++reg) {
            int i = rowBase + wrow + mt * 16 + quad * 4 + reg;
            float sqi = sq[i];
#pragma unroll
            for (int nt = 0; nt < 8; ++nt) {
                int j = colBase + nt * 16 + l15;
                float d2 = sqi + sq[j] - 2.0f * acc[mt][nt][reg];
                float d = sqrtf(fmaxf(d2, 0.0f));
                bool use = i < j;
                lsum += use ? d : 0.f;
                lmin = fminf(lmin, use ? d : INFINITY);
            }
        }
    rs[tid] = lsum; rm[tid] = lmin; __syncthreads();
    for (int s = 128; s > 0; s >>= 1) {
        if (tid < s) { rs[tid] += rs[tid + s]; rm[tid] = fminf(rm[tid], rm[tid + s]); }
        __syncthreads();
    }
    if (tid == 0) { atomicAdd(pairSum, rs[0]); atomicMin(pairMin, f2ord(rm[0])); }
}

// ---- per-row: bit-emulate the reference's fp32 pipeline on candidates ----
__global__ __launch_bounds__(256) void argmax_resolve(const float* __restrict__ lat,
                                                      const float* __restrict__ cb,
                                                      const float* __restrict__ nrml,
                                                      const float* __restrict__ nrmc,
                                                      const ull* __restrict__ keysw,
                                                      float* __restrict__ outidx,
                                                      int* __restrict__ fidx,
                                                      unsigned* __restrict__ counts,
                                                      float* __restrict__ scal) {
    int n = blockIdx.x * 256 + threadIdx.x;
    ull k1 = 0ull;
    for (int j = 0; j < NKEY * NCB; ++j) {
        ull v = keysw[(size_t)j * NTOK + n];
        if (v > k1) k1 = v;
    }
    float v1 = ord2f((unsigned)(k1 >> 32));
    float thresh = v1 - DELTA;
    int cand[MAXC]; int nc = 0;
    for (int j = 0; j < NKEY * NCB; ++j) {
        ull v = keysw[(size_t)j * NTOK + n];
        float val = ord2f((unsigned)(v >> 32));
        if (val >= thresh && nc < MAXC)
            cand[nc++] = (int)(0xFFFFFFFFu - (unsigned)(v & 0xFFFFFFFFull));
    }
    for (int a = 1; a < nc; ++a) {
        int key = cand[a]; int b = a - 1;
        while (b >= 0 && cand[b] > key) { cand[b + 1] = cand[b]; --b; }
        cand[b + 1] = key;
    }
    float nx = nrml[n];
    const float* x = lat + (size_t)n * DIM;
    float bestf = INFINITY, bestm = INFINITY, caf[MAXC];
    int bif = 0x7FFFFFFF, bim = 0x7FFFFFFF;
    for (int c = 0; c < nc; ++c) {
        int k = cand[c];
        const float* cr = cb + (size_t)k * DIM;
        float nk = nrmc[k];
        float af = 0.f, am = 0.f;
        for (int d = 0; d < DIM; ++d) {
            float la = x[d] / nx;       // IEEE fp32 divide
            float cv = cr[d] / nk;
            af = fmaf(la, cv, af);                  // FMA chain
            am = __fadd_rn(am, __fmul_rn(la, cv));  // mul+add chain
        }
        float df = __fsub_rn(2.0f, __fmul_rn(2.0f, af));
        float dm = __fsub_rn(2.0f, __fmul_rn(2.0f, am));
        caf[c] = af;
        if (df < bestf) { bestf = df; bif = k; }
        if (dm < bestm) { bestm = dm; bim = k; }
    }
    int idx = (bif == bim) ? bif : (bif < bim ? bif : bim);
    float selcos = 0.f;
    for (int c = 0; c < nc; ++c) if (cand[c] == idx) selcos = caf[c];
    fidx[n] = idx;
    outidx[n] = (float)idx;
    atomicAdd(&counts[idx], 1u);
    __shared__ float red[256];
    red[threadIdx.x] = selcos; __syncthreads();
    for (int s = 128; s > 0; s >>= 1) {
        if (threadIdx.x < s) red[threadIdx.x] += red[threadIdx.x + s];
        __syncthreads();
    }
    if (threadIdx.x == 0) atomicAdd(&scal[1], red[0]);
}

// ---- gather quantized + mse (16 rows per block) ----
__global__ __launch_bounds__(256) void gather_out(const float* __restrict__ latent,
                                                  const float* __restrict__ codebook,
                                                  const int* __restrict__ fidx,
                                                  float* __restrict__ outq,
                                                  float* __restrict__ scal) {
    int t = threadIdx.x;
    int n0 = blockIdx.x * 16;
    float msePart = 0.f;
    for (int r = 0; r < 16; ++r) {
        int n = n0 + r;
        int idx = fidx[n];
        float q = codebook[(size_t)idx * DIM + t];
        float x = latent[(size_t)n * DIM + t];
        outq[(size_t)n * DIM + t] = q;
        float d = x - q;
        msePart = fmaf(d, d, msePart);
    }
    __shared__ float red[256];
    red[t] = msePart; __syncthreads();
    for (int s = 128; s > 0; s >>= 1) { if (t < s) red[t] += red[t + s]; __syncthreads(); }
    if (t == 0) atomicAdd(&scal[0], red[0]);
}

// ---- scalars ----
__global__ void finalize(const unsigned* __restrict__ counts, const float* __restrict__ scal,
                         const unsigned* __restrict__ pmin, float* __restrict__ outs) {
    int t = threadIdx.x;
    float h = 0.f;
    for (int k = t; k < KCB; k += 256) {
        float p = (float)counts[k] * (1.0f / (float)NTOK);
        h += p * logf(p + 1e-10f);
    }
    __shared__ float red[256];
    red[t] = h; __syncthreads();
    for (int s = 128; s > 0; s >>= 1) { if (t < s) red[t] += red[t + s]; __syncthreads(); }
    if (t == 0) {
        float mse = scal[0] / (float)(NTOK * DIM);
        outs[0] = 0.25f * mse;
        outs[1] = mse;
        outs[2] = expf(-red[0]);
        outs[3] = scal[1] / (float)NTOK;
        outs[4] = scal[2] * 2.0f / ((float)KCB * (float)(KCB - 1));
        outs[5] = ord2f(pmin[0]);
    }
}

extern "C" void kernel_launch(void* const* d_in, const int* in_sizes, int n_in,
                              void* d_out, int out_size, void* d_ws, size_t ws_size,
                              hipStream_t stream) {
    const float* latent = (const float*)d_in[0];    // [8192,256]
    const float* codebook = (const float*)d_in[1];  // [4096,256]
    float* out = (float*)d_out;
    float* outq = out;
    float* outidx = out + (size_t)NTOK * DIM;
    float* outs = outidx + NTOK;

    ull* keysw = (ull*)d_ws;                              // 128*8192 u64 = 8 MB
    ushort* latbf = (ushort*)(keysw + NKEY * NCB * NTOK); // 4 MB
    ushort* cnbf = latbf + (size_t)NTOK * DIM;            // 2 MB
    ushort* cbbf = cnbf + (size_t)KCB * DIM;              // 2 MB
    float* nrml = (float*)(cbbf + (size_t)KCB * DIM);     // 8192
    float* nrmc = nrml + NTOK;                            // 4096
    float* sq = nrmc + KCB;                               // 4096
    int* fidx = (int*)(sq + KCB);                         // 8192
    unsigned* counts = (unsigned*)(fidx + NTOK);          // 4096
    float* scal = (float*)(counts + KCB);                 // [mse, sel, pairsum]
    unsigned* pmin = (unsigned*)(scal + 3);

    hipLaunchKernelGGL(init_ws, dim3((KCB + 255) / 256), dim3(256), 0, stream, counts, scal, pmin);
    hipLaunchKernelGGL(np_norms, dim3(NTOK / 256), dim3(256), 0, stream, latent, nrml, NTOK);
    hipLaunchKernelGGL(np_norms, dim3(KCB / 256), dim3(256), 0, stream, codebook, nrmc, KCB);
    hipLaunchKernelGGL(lat2bf, dim3(NTOK * DIM / 256), dim3(256), 0, stream, latent, latbf);
    hipLaunchKernelGGL(cb_apply, dim3(KCB), dim3(256), 0, stream, codebook, nrmc, cnbf, cbbf, sq);
    hipLaunchKernelGGL(scores_mfma, dim3(NCB, NTOK / 128), dim3(256), 0, stream, latbf, cnbf, keysw);
    hipLaunchKernelGGL(argmax_resolve, dim3(NTOK / 256), dim3(256), 0, stream,
                       latent, codebook, nrml, nrmc, keysw, outidx, fidx, counts, scal);
    hipLaunchKernelGGL(pairwise_mfma, dim3(KCB / 128, KCB / 128), dim3(256), 0, stream, cbbf, sq,
                       &scal[2], pmin);
    hipLaunchKernelGGL(gather_out, dim3(NTOK / 16), dim3(256), 0, stream, latent, codebook, fidx,
                       outq, scal);
    hipLaunchKernelGGL(finalize, dim3(1), dim3(256), 0, stream, counts, scal, pmin, outs);
}

// Round 7
// 294.692 us; speedup vs baseline: 2.9997x; 1.3932x over previous
//
#include <hip/hip_runtime.h>
#include <hip/hip_bf16.h>
#include <math.h>

#define NTOK 8192
#define DIM 256
#define KCB 4096
#define NCB (KCB / 128)   // 32 col-blocks in score GEMM
#define NKEY 4            // top-4 kept per (row, col-block)
#define NKROW (NCB * NKEY) // 128 keys per row
#define DELTA 0.08f       // candidate window, raw-dot units (~20 sigma of bf16 noise)
#define GTIE 2e-6         // fp64 cosine gap below which we run the bit-exact np chain
#define MAXC 16

typedef unsigned long long ull;
typedef unsigned short ushort;
typedef __attribute__((ext_vector_type(8))) short shortx8;   // 8 bf16 (4 VGPRs)
typedef __attribute__((ext_vector_type(4))) float floatx4;
typedef const __attribute__((address_space(1))) void* gas_cp;
typedef __attribute__((address_space(3))) void* las_p;

// ---- float <-> order-preserving u32 ----
__device__ __forceinline__ unsigned f2ord(float f) {
    unsigned u = __float_as_uint(f);
    return (u & 0x80000000u) ? ~u : (u | 0x80000000u);
}
__device__ __forceinline__ float ord2f(unsigned u) {
    unsigned b = (u & 0x80000000u) ? (u & 0x7FFFFFFFu) : ~u;
    return __uint_as_float(b);
}
__device__ __forceinline__ ushort f2bf(float f) {   // RNE fp32->bf16
    unsigned u = __float_as_uint(f);
    unsigned r = u + 0x7FFFu + ((u >> 16) & 1u);
    return (ushort)(r >> 16);
}

// ---- shared-memory union: GEMM tiles alias the epilogue key store ----
union TileSmem {
    struct { ushort a[128][64]; ushort b[128][64]; } t;   // 32 KB
    ull keys[128][33];                                    // 33 KB (+pad col)
};

// ---- async stage: 128 rows x 64 ushorts, XOR-swizzled chunks ----
__device__ __forceinline__ void stage_tile(const ushort* __restrict__ gbase,
                                           ushort (*lds)[64], int wave, int lane,
                                           int kk) {
    int p = lane & 7;
    int rsub = lane >> 3;
    int kc = p ^ (rsub & 7);
#pragma unroll
    for (int c = 0; c < 4; ++c) {
        int j = wave * 4 + c;
        const ushort* src = gbase + (size_t)(j * 8 + rsub) * DIM + kk + kc * 8;
        __builtin_amdgcn_global_load_lds((gas_cp)src, (las_p)&lds[j * 8][0], 16, 0, 0);
    }
}
__device__ __forceinline__ shortx8 frag_read(const ushort (*lds)[64], int row,
                                             int lc) {
    return *(const shortx8*)&lds[row][(lc ^ (row & 7)) * 8];
}

// ---- numpy float32 pairwise-sum norm over 256 contiguous elements ----
__device__ float np_norm256(const float* __restrict__ a) {
    float half[2];
#pragma unroll 1
    for (int h = 0; h < 2; ++h) {
        const float* p = a + h * 128;
        float r[8];
#pragma unroll
        for (int j = 0; j < 8; ++j) r[j] = __fmul_rn(p[j], p[j]);
#pragma unroll 1
        for (int i = 8; i < 128; i += 8)
#pragma unroll
            for (int j = 0; j < 8; ++j)
                r[j] = __fadd_rn(r[j], __fmul_rn(p[i + j], p[i + j]));
        float t0 = __fadd_rn(r[0], r[1]);
        float t1 = __fadd_rn(r[2], r[3]);
        float t2 = __fadd_rn(r[4], r[5]);
        float t3 = __fadd_rn(r[6], r[7]);
        half[h] = __fadd_rn(__fadd_rn(t0, t1), __fadd_rn(t2, t3));
    }
    float s = __fadd_rn(half[0], half[1]);
    return fmaxf(sqrtf(s), 1e-12f);
}

__global__ void init_ws(unsigned* counts, float* scal, unsigned* pmin) {
    int i = blockIdx.x * blockDim.x + threadIdx.x;
    if (i < KCB) counts[i] = 0u;
    if (i == 0) { scal[0] = 0.f; scal[1] = 0.f; scal[2] = 0.f; pmin[0] = 0xFFFFFFFFu; }
}

__global__ void np_norms(const float* __restrict__ src, float* __restrict__ nrm, int nrows) {
    int r = blockIdx.x * blockDim.x + threadIdx.x;
    if (r < nrows) nrm[r] = np_norm256(src + (size_t)r * DIM);
}

__global__ void lat2bf(const float* __restrict__ lat, ushort* __restrict__ latbf) {
    int i = blockIdx.x * blockDim.x + threadIdx.x;
    latbf[i] = f2bf(lat[i]);
}

__global__ void cb_apply(const float* __restrict__ cb, const float* __restrict__ nrmc,
                         ushort* __restrict__ cnbf, ushort* __restrict__ cbbf,
                         float* __restrict__ sq) {
    int n = blockIdx.x, t = threadIdx.x;
    float c = cb[n * DIM + t];
    cnbf[n * DIM + t] = f2bf(c / nrmc[n]);
    cbbf[n * DIM + t] = f2bf(c);
    __shared__ double red[256];
    red[t] = (double)c * (double)c; __syncthreads();
    for (int s = 128; s > 0; s >>= 1) { if (t < s) red[t] += red[t + s]; __syncthreads(); }
    if (t == 0) sq[n] = (float)red[0];
}

// ---- bf16 MFMA score GEMM + branchless per-row top-4 per 128-col block ----
__global__ __launch_bounds__(256) void scores_mfma(const ushort* __restrict__ A,
                                                   const ushort* __restrict__ B,
                                                   ull* __restrict__ keysw) {
    __shared__ TileSmem sm;
    int tid = threadIdx.x;
    int wave = tid >> 6, lane = tid & 63;
    int quad = lane >> 4, l15 = lane & 15;
    int rowBase = blockIdx.y * 128, colBase = blockIdx.x * 128;
    int wrow = wave * 32;
    floatx4 acc[2][8];
#pragma unroll
    for (int m = 0; m < 2; ++m)
#pragma unroll
        for (int n = 0; n < 8; ++n) acc[m][n] = (floatx4){0.f, 0.f, 0.f, 0.f};
    const ushort* gA = A + (size_t)rowBase * DIM;
    const ushort* gB = B + (size_t)colBase * DIM;
#pragma unroll 1
    for (int kk = 0; kk < DIM; kk += 64) {
        __syncthreads();
        stage_tile(gA, sm.t.a, wave, lane, kk);
        stage_tile(gB, sm.t.b, wave, lane, kk);
        __syncthreads();
#pragma unroll
        for (int s = 0; s < 2; ++s) {
            shortx8 af[2], bf[8];
#pragma unroll
            for (int mt = 0; mt < 2; ++mt)
                af[mt] = frag_read(sm.t.a, wrow + mt * 16 + l15, s * 4 + quad);
#pragma unroll
            for (int nt = 0; nt < 8; ++nt)
                bf[nt] = frag_read(sm.t.b, nt * 16 + l15, s * 4 + quad);
#pragma unroll
            for (int mt = 0; mt < 2; ++mt)
#pragma unroll
                for (int nt = 0; nt < 8; ++nt)
                    acc[mt][nt] = __builtin_amdgcn_mfma_f32_16x16x32_bf16(
                        af[mt], bf[nt], acc[mt][nt], 0, 0, 0);
        }
    }
    __syncthreads();   // tiles dead; reuse LDS as keys
#pragma unroll
    for (int mt = 0; mt < 2; ++mt)
#pragma unroll
        for (int reg = 0; reg < 4; ++reg) {
            ull b1 = 0ull, b2 = 0ull;
#pragma unroll
            for (int nt = 0; nt < 8; ++nt) {
                unsigned col = (unsigned)(colBase + nt * 16 + l15);
                ull key = ((ull)f2ord(acc[mt][nt][reg]) << 32) |
                          (ull)(0xFFFFFFFFu - col);
                ull lo = key < b1 ? key : b1;
                b1 = key > b1 ? key : b1;
                b2 = lo > b2 ? lo : b2;
            }
            int row = wrow + mt * 16 + quad * 4 + reg;
            sm.keys[row][l15 * 2] = b1;
            sm.keys[row][l15 * 2 + 1] = b2;
        }
    __syncthreads();
    if (tid < 128) {
        ull a0 = 0, a1 = 0, a2 = 0, a3 = 0;
#pragma unroll
        for (int j = 0; j < 32; ++j) {
            ull v = sm.keys[tid][j];
            ull n0 = v < a0 ? v : a0; a0 = v > a0 ? v : a0;
            ull n1 = n0 < a1 ? n0 : a1; a1 = n0 > a1 ? n0 : a1;
            ull n2 = n1 < a2 ? n1 : a2; a2 = n1 > a2 ? n1 : a2;
            a3 = n2 > a3 ? n2 : a3;
        }
        // row-major: keys of row r contiguous [r][128]
        size_t base = (size_t)(rowBase + tid) * NKROW + blockIdx.x * NKEY;
        keysw[base] = a0;
        keysw[base + 1] = a1;
        keysw[base + 2] = a2;
        keysw[base + 3] = a3;
    }
}

// ---- bf16 MFMA codebook pairwise: upper-triangle tiles, fused sum/min ----
__global__ __launch_bounds__(256) void pairwise_mfma(const ushort* __restrict__ C,
                                                     const float* __restrict__ sq,
                                                     float* __restrict__ pairSum,
                                                     unsigned* __restrict__ pairMin) {
    if (blockIdx.y > blockIdx.x) return;
    __shared__ TileSmem sm;
    __shared__ float rs[256], rm[256];
    int tid = threadIdx.x;
    int wave = tid >> 6, lane = tid & 63;
    int quad = lane >> 4, l15 = lane & 15;
    int rowBase = blockIdx.y * 128, colBase = blockIdx.x * 128;
    int wrow = wave * 32;
    floatx4 acc[2][8];
#pragma unroll
    for (int m = 0; m < 2; ++m)
#pragma unroll
        for (int n = 0; n < 8; ++n) acc[m][n] = (floatx4){0.f, 0.f, 0.f, 0.f};
    const ushort* gA = C + (size_t)rowBase * DIM;
    const ushort* gB = C + (size_t)colBase * DIM;
#pragma unroll 1
    for (int kk = 0; kk < DIM; kk += 64) {
        __syncthreads();
        stage_tile(gA, sm.t.a, wave, lane, kk);
        stage_tile(gB, sm.t.b, wave, lane, kk);
        __syncthreads();
#pragma unroll
        for (int s = 0; s < 2; ++s) {
            shortx8 af[2], bf[8];
#pragma unroll
            for (int mt = 0; mt < 2; ++mt)
                af[mt] = frag_read(sm.t.a, wrow + mt * 16 + l15, s * 4 + quad);
#pragma unroll
            for (int nt = 0; nt < 8; ++nt)
                bf[nt] = frag_read(sm.t.b, nt * 16 + l15, s * 4 + quad);
#pragma unroll
            for (int mt = 0; mt < 2; ++mt)
#pragma unroll
                for (int nt = 0; nt < 8; ++nt)
                    acc[mt][nt] = __builtin_amdgcn_mfma_f32_16x16x32_bf16(
                        af[mt], bf[nt], acc[mt][nt], 0, 0, 0);
        }
    }
    float lsum = 0.f, lmin = INFINITY;
#pragma unroll
    for (int mt = 0; mt < 2; ++mt)
#pragma unroll
        for (int reg = 0; reg < 4; ++reg) {
            int i = rowBase + wrow + mt * 16 + quad * 4 + reg;
            float sqi = sq[i];
#pragma unroll
            for (int nt = 0; nt < 8; ++nt) {
                int j = colBase + nt * 16 + l15;
                float d2 = sqi + sq[j] - 2.0f * acc[mt][nt][reg];
                float d = sqrtf(fmaxf(d2, 0.0f));
                bool use = i < j;
                lsum += use ? d : 0.f;
                lmin = fminf(lmin, use ? d : INFINITY);
            }
        }
    rs[tid] = lsum; rm[tid] = lmin; __syncthreads();
    for (int s = 128; s > 0; s >>= 1) {
        if (tid < s) { rs[tid] += rs[tid + s]; rm[tid] = fminf(rm[tid], rm[tid + s]); }
        __syncthreads();
    }
    if (tid == 0) { atomicAdd(pairSum, rs[0]); atomicMin(pairMin, f2ord(rm[0])); }
}

// ---- wave-per-row argmax resolve: ballot compaction, fp64 rescore, np-chain ----
// No __syncthreads (divergent paths): LDS is wave-private, fenced.
__global__ __launch_bounds__(256) void argmax_resolve(const float* __restrict__ lat,
                                                      const float* __restrict__ cb,
                                                      const float* __restrict__ nrml,
                                                      const float* __restrict__ nrmc,
                                                      const ull* __restrict__ keysw,
                                                      float* __restrict__ outidx,
                                                      int* __restrict__ fidx,
                                                      unsigned* __restrict__ counts,
                                                      float* __restrict__ scal) {
    __shared__ int scand[4][MAXC];
    __shared__ double sc64[4][MAXC];
    int wid = threadIdx.x >> 6, lane = threadIdx.x & 63;
    int n = blockIdx.x * 4 + wid;
    const ull* kr = keysw + (size_t)n * NKROW;
    ull k0 = kr[lane * 2];
    ull k1 = kr[lane * 2 + 1];
    ull m = k0 > k1 ? k0 : k1;
#pragma unroll
    for (int off = 1; off < 64; off <<= 1) {
        ull o = __shfl_xor(m, off, 64);
        m = o > m ? o : m;
    }
    float v1 = ord2f((unsigned)(m >> 32));
    float thresh = v1 - DELTA;
    bool p0 = ord2f((unsigned)(k0 >> 32)) >= thresh;
    bool p1 = ord2f((unsigned)(k1 >> 32)) >= thresh;
    ull b0 = __ballot(p0), b1 = __ballot(p1);
    int below0 = __builtin_amdgcn_mbcnt_hi((unsigned)(b0 >> 32),
                 __builtin_amdgcn_mbcnt_lo((unsigned)b0, 0));
    int below1 = __builtin_amdgcn_mbcnt_hi((unsigned)(b1 >> 32),
                 __builtin_amdgcn_mbcnt_lo((unsigned)b1, 0));
    int base1 = __popcll(b0);
    int nc = base1 + __popcll(b1);
    if (p0 && below0 < MAXC)
        scand[wid][below0] = (int)(0xFFFFFFFFu - (unsigned)(k0 & 0xFFFFFFFFull));
    if (p1 && base1 + below1 < MAXC)
        scand[wid][base1 + below1] = (int)(0xFFFFFFFFu - (unsigned)(k1 & 0xFFFFFFFFull));
    nc = nc < MAXC ? nc : MAXC;
    __threadfence_block();
    float nx = nrml[n];
    int idx; float selcos;
    if (nc <= 1) {
        idx = (int)(0xFFFFFFFFu - (unsigned)(m & 0xFFFFFFFFull));
        selcos = v1 / nx;
    } else {
        // wave-cooperative fp64 rescore of each candidate
        int d0 = lane * 4;
        float4 xv = *(const float4*)(lat + (size_t)n * DIM + d0);
        float la0 = xv.x / nx, la1 = xv.y / nx, la2 = xv.z / nx, la3 = xv.w / nx;
        for (int c = 0; c < nc; ++c) {
            int k = scand[wid][c];
            float nk = nrmc[k];
            float4 cv = *(const float4*)(cb + (size_t)k * DIM + d0);
            double part = (double)(cv.x / nk) * la0 + (double)(cv.y / nk) * la1 +
                          (double)(cv.z / nk) * la2 + (double)(cv.w / nk) * la3;
#pragma unroll
            for (int off = 1; off < 64; off <<= 1) part += __shfl_xor(part, off, 64);
            if (lane == 0) sc64[wid][c] = part;
        }
        __threadfence_block();
        double best64 = -1e300;
        for (int c = 0; c < nc; ++c) best64 = fmax(best64, sc64[wid][c]);
        int nrisk = 0;
        for (int c = 0; c < nc; ++c) if (sc64[wid][c] >= best64 - GTIE) ++nrisk;
        if (nrisk == 1) {
            idx = 0x7FFFFFFF; selcos = 0.f;
            for (int c = 0; c < nc; ++c)
                if (sc64[wid][c] >= best64 - GTIE) { idx = scand[wid][c]; selcos = (float)sc64[wid][c]; }
        } else {
            // rare: bit-exact np fp32 chains, one candidate per lane (R4 semantics)
            ull keyf = 0ull, keym = 0ull;
            if (lane < nc && sc64[wid][lane] >= best64 - GTIE) {
                int k = scand[wid][lane];
                const float* cr = cb + (size_t)k * DIM;
                const float* x = lat + (size_t)n * DIM;
                float nk = nrmc[k];
                float af = 0.f, am = 0.f;
                for (int d = 0; d < DIM; ++d) {
                    float la = x[d] / nx;
                    float cv = cr[d] / nk;
                    af = fmaf(la, cv, af);
                    am = __fadd_rn(am, __fmul_rn(la, cv));
                }
                float df = __fsub_rn(2.0f, __fmul_rn(2.0f, af));
                float dm = __fsub_rn(2.0f, __fmul_rn(2.0f, am));
                keyf = ((ull)(0xFFFFFFFFu - f2ord(df)) << 32) | (ull)(0xFFFFFFFFu - (unsigned)k);
                keym = ((ull)(0xFFFFFFFFu - f2ord(dm)) << 32) | (ull)(0xFFFFFFFFu - (unsigned)k);
            }
#pragma unroll
            for (int off = 1; off < 64; off <<= 1) {
                ull of = __shfl_xor(keyf, off, 64);
                ull om = __shfl_xor(keym, off, 64);
                keyf = of > keyf ? of : keyf;
                keym = om > keym ? om : keym;
            }
            int colf = (int)(0xFFFFFFFFu - (unsigned)(keyf & 0xFFFFFFFFull));
            int colm = (int)(0xFFFFFFFFu - (unsigned)(keym & 0xFFFFFFFFull));
            idx = colf < colm ? colf : colm;
            selcos = 0.f;
            for (int c = 0; c < nc; ++c)
                if (scand[wid][c] == idx) selcos = (float)sc64[wid][c];
        }
    }
    if (lane == 0) {
        fidx[n] = idx;
        outidx[n] = (float)idx;
        atomicAdd(&counts[idx], 1u);
        atomicAdd(&scal[1], selcos);
    }
}

// ---- gather quantized + mse (16 rows per block) ----
__global__ __launch_bounds__(256) void gather_out(const float* __restrict__ latent,
                                                  const float* __restrict__ codebook,
                                                  const int* __restrict__ fidx,
                                                  float* __restrict__ outq,
                                                  float* __restrict__ scal) {
    int t = threadIdx.x;
    int n0 = blockIdx.x * 16;
    float msePart = 0.f;
    for (int r = 0; r < 16; ++r) {
        int n = n0 + r;
        int idx = fidx[n];
        float q = codebook[(size_t)idx * DIM + t];
        float x = latent[(size_t)n * DIM + t];
        outq[(size_t)n * DIM + t] = q;
        float d = x - q;
        msePart = fmaf(d, d, msePart);
    }
    __shared__ float red[256];
    red[t] = msePart; __syncthreads();
    for (int s = 128; s > 0; s >>= 1) { if (t < s) red[t] += red[t + s]; __syncthreads(); }
    if (t == 0) atomicAdd(&scal[0], red[0]);
}

// ---- scalars ----
__global__ void finalize(const unsigned* __restrict__ counts, const float* __restrict__ scal,
                         const unsigned* __restrict__ pmin, float* __restrict__ outs) {
    int t = threadIdx.x;
    float h = 0.f;
    for (int k = t; k < KCB; k += 256) {
        float p = (float)counts[k] * (1.0f / (float)NTOK);
        h += p * logf(p + 1e-10f);
    }
    __shared__ float red[256];
    red[t] = h; __syncthreads();
    for (int s = 128; s > 0; s >>= 1) { if (t < s) red[t] += red[t + s]; __syncthreads(); }
    if (t == 0) {
        float mse = scal[0] / (float)(NTOK * DIM);
        outs[0] = 0.25f * mse;
        outs[1] = mse;
        outs[2] = expf(-red[0]);
        outs[3] = scal[1] / (float)NTOK;
        outs[4] = scal[2] * 2.0f / ((float)KCB * (float)(KCB - 1));
        outs[5] = ord2f(pmin[0]);
    }
}

extern "C" void kernel_launch(void* const* d_in, const int* in_sizes, int n_in,
                              void* d_out, int out_size, void* d_ws, size_t ws_size,
                              hipStream_t stream) {
    const float* latent = (const float*)d_in[0];    // [8192,256]
    const float* codebook = (const float*)d_in[1];  // [4096,256]
    float* out = (float*)d_out;
    float* outq = out;
    float* outidx = out + (size_t)NTOK * DIM;
    float* outs = outidx + NTOK;

    ull* keysw = (ull*)d_ws;                              // 128*8192 u64 = 8 MB
    ushort* latbf = (ushort*)(keysw + (size_t)NKROW * NTOK); // 4 MB
    ushort* cnbf = latbf + (size_t)NTOK * DIM;            // 2 MB
    ushort* cbbf = cnbf + (size_t)KCB * DIM;              // 2 MB
    float* nrml = (float*)(cbbf + (size_t)KCB * DIM);     // 8192
    float* nrmc = nrml + NTOK;                            // 4096
    float* sq = nrmc + KCB;                               // 4096
    int* fidx = (int*)(sq + KCB);                         // 8192
    unsigned* counts = (unsigned*)(fidx + NTOK);          // 4096
    float* scal = (float*)(counts + KCB);                 // [mse, sel, pairsum]
    unsigned* pmin = (unsigned*)(scal + 3);

    hipLaunchKernelGGL(init_ws, dim3((KCB + 255) / 256), dim3(256), 0, stream, counts, scal, pmin);
    hipLaunchKernelGGL(np_norms, dim3(NTOK / 256), dim3(256), 0, stream, latent, nrml, NTOK);
    hipLaunchKernelGGL(np_norms, dim3(KCB / 256), dim3(256), 0, stream, codebook, nrmc, KCB);
    hipLaunchKernelGGL(lat2bf, dim3(NTOK * DIM / 256), dim3(256), 0, stream, latent, latbf);
    hipLaunchKernelGGL(cb_apply, dim3(KCB), dim3(256), 0, stream, codebook, nrmc, cnbf, cbbf, sq);
    hipLaunchKernelGGL(scores_mfma, dim3(NCB, NTOK / 128), dim3(256), 0, stream, latbf, cnbf, keysw);
    hipLaunchKernelGGL(argmax_resolve, dim3(NTOK / 4), dim3(256), 0, stream,
                       latent, codebook, nrml, nrmc, keysw, outidx, fidx, counts, scal);
    hipLaunchKernelGGL(pairwise_mfma, dim3(KCB / 128, KCB / 128), dim3(256), 0, stream, cbbf, sq,
                       &scal[2], pmin);
    hipLaunchKernelGGL(gather_out, dim3(NTOK / 16), dim3(256), 0, stream, latent, codebook, fidx,
                       outq, scal);
    hipLaunchKernelGGL(finalize, dim3(1), dim3(256), 0, stream, counts, scal, pmin, outs);
}

// Round 8
// 211.303 us; speedup vs baseline: 4.1835x; 1.3946x over previous
//
#include <hip/hip_runtime.h>
#include <hip/hip_bf16.h>
#include <math.h>

#define NTOK 8192
#define DIM 256
#define KCB 4096
#define NCB (KCB / 128)    // 32 col-blocks in score GEMM
#define NKEY 4             // top-4 kept per (row, col-block)
#define NKROW (NCB * NKEY) // 128 keys per row
#define DELTA 0.08f        // candidate window, raw-dot units (~20 sigma of bf16 noise)
#define GTIE 2e-6          // fp64 cosine gap below which we run the bit-exact np chain
#define MAXC 16
#define NPAIRB (NCB * NCB) // 1024 pairwise blocks
#define NGATB (NTOK / 16)  // 512 gather blocks

typedef unsigned long long ull;
typedef unsigned short ushort;
typedef __attribute__((ext_vector_type(8))) short shortx8;   // 8 bf16 (4 VGPRs)
typedef __attribute__((ext_vector_type(4))) float floatx4;
typedef const __attribute__((address_space(1))) void* gas_cp;
typedef __attribute__((address_space(3))) void* las_p;

// ---- float <-> order-preserving u32 ----
__device__ __forceinline__ unsigned f2ord(float f) {
    unsigned u = __float_as_uint(f);
    return (u & 0x80000000u) ? ~u : (u | 0x80000000u);
}
__device__ __forceinline__ float ord2f(unsigned u) {
    unsigned b = (u & 0x80000000u) ? (u & 0x7FFFFFFFu) : ~u;
    return __uint_as_float(b);
}
__device__ __forceinline__ ushort f2bf(float f) {   // RNE fp32->bf16
    unsigned u = __float_as_uint(f);
    unsigned r = u + 0x7FFFu + ((u >> 16) & 1u);
    return (ushort)(r >> 16);
}

// ---- shared-memory union: GEMM tiles alias the epilogue key store ----
union TileSmem {
    struct { ushort a[128][64]; ushort b[128][64]; } t;   // 32 KB
    ull keys[128][33];                                    // 33 KB (+pad col)
};

// ---- async stage: 128 rows x 64 ushorts, XOR-swizzled chunks ----
__device__ __forceinline__ void stage_tile(const ushort* __restrict__ gbase,
                                           ushort (*lds)[64], int wave, int lane,
                                           int kk) {
    int p = lane & 7;
    int rsub = lane >> 3;
    int kc = p ^ (rsub & 7);
#pragma unroll
    for (int c = 0; c < 4; ++c) {
        int j = wave * 4 + c;
        const ushort* src = gbase + (size_t)(j * 8 + rsub) * DIM + kk + kc * 8;
        __builtin_amdgcn_global_load_lds((gas_cp)src, (las_p)&lds[j * 8][0], 16, 0, 0);
    }
}
__device__ __forceinline__ shortx8 frag_read(const ushort (*lds)[64], int row,
                                             int lc) {
    return *(const shortx8*)&lds[row][(lc ^ (row & 7)) * 8];
}

// ---- numpy float32 pairwise-sum norm over 256 contiguous elements ----
__device__ float np_norm256(const float* __restrict__ a) {
    float half[2];
#pragma unroll 1
    for (int h = 0; h < 2; ++h) {
        const float* p = a + h * 128;
        float r[8];
#pragma unroll
        for (int j = 0; j < 8; ++j) r[j] = __fmul_rn(p[j], p[j]);
#pragma unroll 1
        for (int i = 8; i < 128; i += 8)
#pragma unroll
            for (int j = 0; j < 8; ++j)
                r[j] = __fadd_rn(r[j], __fmul_rn(p[i + j], p[i + j]));
        float t0 = __fadd_rn(r[0], r[1]);
        float t1 = __fadd_rn(r[2], r[3]);
        float t2 = __fadd_rn(r[4], r[5]);
        float t3 = __fadd_rn(r[6], r[7]);
        half[h] = __fadd_rn(__fadd_rn(t0, t1), __fadd_rn(t2, t3));
    }
    float s = __fadd_rn(half[0], half[1]);
    return fmaxf(sqrtf(s), 1e-12f);
}

__global__ void init_ws(unsigned* counts) {
    int i = blockIdx.x * blockDim.x + threadIdx.x;
    if (i < KCB) counts[i] = 0u;
}

__global__ void np_norms(const float* __restrict__ src, float* __restrict__ nrm, int nrows) {
    int r = blockIdx.x * blockDim.x + threadIdx.x;
    if (r < nrows) nrm[r] = np_norm256(src + (size_t)r * DIM);
}

__global__ void lat2bf(const float* __restrict__ lat, ushort* __restrict__ latbf) {
    int i = blockIdx.x * blockDim.x + threadIdx.x;
    latbf[i] = f2bf(lat[i]);
}

__global__ void cb_apply(const float* __restrict__ cb, const float* __restrict__ nrmc,
                         ushort* __restrict__ cnbf, ushort* __restrict__ cbbf,
                         float* __restrict__ sq) {
    int n = blockIdx.x, t = threadIdx.x;
    float c = cb[n * DIM + t];
    cnbf[n * DIM + t] = f2bf(c / nrmc[n]);
    cbbf[n * DIM + t] = f2bf(c);
    __shared__ double red[256];
    red[t] = (double)c * (double)c; __syncthreads();
    for (int s = 128; s > 0; s >>= 1) { if (t < s) red[t] += red[t + s]; __syncthreads(); }
    if (t == 0) sq[n] = (float)red[0];
}

// ---- bf16 MFMA score GEMM + branchless per-row top-4 per 128-col block ----
__global__ __launch_bounds__(256) void scores_mfma(const ushort* __restrict__ A,
                                                   const ushort* __restrict__ B,
                                                   ull* __restrict__ keysw) {
    __shared__ TileSmem sm;
    int tid = threadIdx.x;
    int wave = tid >> 6, lane = tid & 63;
    int quad = lane >> 4, l15 = lane & 15;
    int rowBase = blockIdx.y * 128, colBase = blockIdx.x * 128;
    int wrow = wave * 32;
    floatx4 acc[2][8];
#pragma unroll
    for (int m = 0; m < 2; ++m)
#pragma unroll
        for (int n = 0; n < 8; ++n) acc[m][n] = (floatx4){0.f, 0.f, 0.f, 0.f};
    const ushort* gA = A + (size_t)rowBase * DIM;
    const ushort* gB = B + (size_t)colBase * DIM;
#pragma unroll 1
    for (int kk = 0; kk < DIM; kk += 64) {
        __syncthreads();
        stage_tile(gA, sm.t.a, wave, lane, kk);
        stage_tile(gB, sm.t.b, wave, lane, kk);
        __syncthreads();
#pragma unroll
        for (int s = 0; s < 2; ++s) {
            shortx8 af[2], bf[8];
#pragma unroll
            for (int mt = 0; mt < 2; ++mt)
                af[mt] = frag_read(sm.t.a, wrow + mt * 16 + l15, s * 4 + quad);
#pragma unroll
            for (int nt = 0; nt < 8; ++nt)
                bf[nt] = frag_read(sm.t.b, nt * 16 + l15, s * 4 + quad);
#pragma unroll
            for (int mt = 0; mt < 2; ++mt)
#pragma unroll
                for (int nt = 0; nt < 8; ++nt)
                    acc[mt][nt] = __builtin_amdgcn_mfma_f32_16x16x32_bf16(
                        af[mt], bf[nt], acc[mt][nt], 0, 0, 0);
        }
    }
    __syncthreads();   // tiles dead; reuse LDS as keys
#pragma unroll
    for (int mt = 0; mt < 2; ++mt)
#pragma unroll
        for (int reg = 0; reg < 4; ++reg) {
            ull b1 = 0ull, b2 = 0ull;
#pragma unroll
            for (int nt = 0; nt < 8; ++nt) {
                unsigned col = (unsigned)(colBase + nt * 16 + l15);
                ull key = ((ull)f2ord(acc[mt][nt][reg]) << 32) |
                          (ull)(0xFFFFFFFFu - col);
                ull lo = key < b1 ? key : b1;
                b1 = key > b1 ? key : b1;
                b2 = lo > b2 ? lo : b2;
            }
            int row = wrow + mt * 16 + quad * 4 + reg;
            sm.keys[row][l15 * 2] = b1;
            sm.keys[row][l15 * 2 + 1] = b2;
        }
    __syncthreads();
    if (tid < 128) {
        ull a0 = 0, a1 = 0, a2 = 0, a3 = 0;
#pragma unroll
        for (int j = 0; j < 32; ++j) {
            ull v = sm.keys[tid][j];
            ull n0 = v < a0 ? v : a0; a0 = v > a0 ? v : a0;
            ull n1 = n0 < a1 ? n0 : a1; a1 = n0 > a1 ? n0 : a1;
            ull n2 = n1 < a2 ? n1 : a2; a2 = n1 > a2 ? n1 : a2;
            a3 = n2 > a3 ? n2 : a3;
        }
        size_t base = (size_t)(rowBase + tid) * NKROW + blockIdx.x * NKEY;
        keysw[base] = a0;
        keysw[base + 1] = a1;
        keysw[base + 2] = a2;
        keysw[base + 3] = a3;
    }
}

// ---- bf16 MFMA codebook pairwise: per-block partials, no atomics ----
__global__ __launch_bounds__(256) void pairwise_mfma(const ushort* __restrict__ C,
                                                     const float* __restrict__ sq,
                                                     float* __restrict__ psumw,
                                                     unsigned* __restrict__ pminw) {
    int bid = blockIdx.y * NCB + blockIdx.x;
    if (blockIdx.y > blockIdx.x) {
        if (threadIdx.x == 0) { psumw[bid] = 0.f; pminw[bid] = 0xFFFFFFFFu; }
        return;
    }
    __shared__ TileSmem sm;
    __shared__ float rs[256], rm[256];
    int tid = threadIdx.x;
    int wave = tid >> 6, lane = tid & 63;
    int quad = lane >> 4, l15 = lane & 15;
    int rowBase = blockIdx.y * 128, colBase = blockIdx.x * 128;
    int wrow = wave * 32;
    floatx4 acc[2][8];
#pragma unroll
    for (int m = 0; m < 2; ++m)
#pragma unroll
        for (int n = 0; n < 8; ++n) acc[m][n] = (floatx4){0.f, 0.f, 0.f, 0.f};
    const ushort* gA = C + (size_t)rowBase * DIM;
    const ushort* gB = C + (size_t)colBase * DIM;
#pragma unroll 1
    for (int kk = 0; kk < DIM; kk += 64) {
        __syncthreads();
        stage_tile(gA, sm.t.a, wave, lane, kk);
        stage_tile(gB, sm.t.b, wave, lane, kk);
        __syncthreads();
#pragma unroll
        for (int s = 0; s < 2; ++s) {
            shortx8 af[2], bf[8];
#pragma unroll
            for (int mt = 0; mt < 2; ++mt)
                af[mt] = frag_read(sm.t.a, wrow + mt * 16 + l15, s * 4 + quad);
#pragma unroll
            for (int nt = 0; nt < 8; ++nt)
                bf[nt] = frag_read(sm.t.b, nt * 16 + l15, s * 4 + quad);
#pragma unroll
            for (int mt = 0; mt < 2; ++mt)
#pragma unroll
                for (int nt = 0; nt < 8; ++nt)
                    acc[mt][nt] = __builtin_amdgcn_mfma_f32_16x16x32_bf16(
                        af[mt], bf[nt], acc[mt][nt], 0, 0, 0);
        }
    }
    float lsum = 0.f, lmin = INFINITY;
#pragma unroll
    for (int mt = 0; mt < 2; ++mt)
#pragma unroll
        for (int reg = 0; reg < 4; ++reg) {
            int i = rowBase + wrow + mt * 16 + quad * 4 + reg;
            float sqi = sq[i];
#pragma unroll
            for (int nt = 0; nt < 8; ++nt) {
                int j = colBase + nt * 16 + l15;
                float d2 = sqi + sq[j] - 2.0f * acc[mt][nt][reg];
                float d = sqrtf(fmaxf(d2, 0.0f));
                bool use = i < j;
                lsum += use ? d : 0.f;
                lmin = fminf(lmin, use ? d : INFINITY);
            }
        }
    rs[tid] = lsum; rm[tid] = lmin; __syncthreads();
    for (int s = 128; s > 0; s >>= 1) {
        if (tid < s) { rs[tid] += rs[tid + s]; rm[tid] = fminf(rm[tid], rm[tid + s]); }
        __syncthreads();
    }
    if (tid == 0) { psumw[bid] = rs[0]; pminw[bid] = f2ord(rm[0]); }
}

// ---- wave-per-row argmax resolve: no contended atomics ----
__global__ __launch_bounds__(256) void argmax_resolve(const float* __restrict__ lat,
                                                      const float* __restrict__ cb,
                                                      const float* __restrict__ nrml,
                                                      const float* __restrict__ nrmc,
                                                      const ull* __restrict__ keysw,
                                                      float* __restrict__ outidx,
                                                      int* __restrict__ fidx,
                                                      unsigned* __restrict__ counts,
                                                      float* __restrict__ selw) {
    __shared__ int scand[4][MAXC];
    __shared__ double sc64[4][MAXC];
    int wid = threadIdx.x >> 6, lane = threadIdx.x & 63;
    int n = blockIdx.x * 4 + wid;
    const ull* kr = keysw + (size_t)n * NKROW;
    ull k0 = kr[lane * 2];
    ull k1 = kr[lane * 2 + 1];
    ull m = k0 > k1 ? k0 : k1;
#pragma unroll
    for (int off = 1; off < 64; off <<= 1) {
        ull o = __shfl_xor(m, off, 64);
        m = o > m ? o : m;
    }
    float v1 = ord2f((unsigned)(m >> 32));
    float thresh = v1 - DELTA;
    bool p0 = ord2f((unsigned)(k0 >> 32)) >= thresh;
    bool p1 = ord2f((unsigned)(k1 >> 32)) >= thresh;
    ull b0 = __ballot(p0), b1 = __ballot(p1);
    int below0 = __builtin_amdgcn_mbcnt_hi((unsigned)(b0 >> 32),
                 __builtin_amdgcn_mbcnt_lo((unsigned)b0, 0));
    int below1 = __builtin_amdgcn_mbcnt_hi((unsigned)(b1 >> 32),
                 __builtin_amdgcn_mbcnt_lo((unsigned)b1, 0));
    int base1 = __popcll(b0);
    int nc = base1 + __popcll(b1);
    if (p0 && below0 < MAXC)
        scand[wid][below0] = (int)(0xFFFFFFFFu - (unsigned)(k0 & 0xFFFFFFFFull));
    if (p1 && base1 + below1 < MAXC)
        scand[wid][base1 + below1] = (int)(0xFFFFFFFFu - (unsigned)(k1 & 0xFFFFFFFFull));
    nc = nc < MAXC ? nc : MAXC;
    __threadfence_block();
    float nx = nrml[n];
    int idx; float selcos;
    if (nc <= 1) {
        idx = (int)(0xFFFFFFFFu - (unsigned)(m & 0xFFFFFFFFull));
        selcos = v1 / nx;
    } else {
        int d0 = lane * 4;
        float4 xv = *(const float4*)(lat + (size_t)n * DIM + d0);
        float la0 = xv.x / nx, la1 = xv.y / nx, la2 = xv.z / nx, la3 = xv.w / nx;
        for (int c = 0; c < nc; ++c) {
            int k = scand[wid][c];
            float nk = nrmc[k];
            float4 cv = *(const float4*)(cb + (size_t)k * DIM + d0);
            double part = (double)(cv.x / nk) * la0 + (double)(cv.y / nk) * la1 +
                          (double)(cv.z / nk) * la2 + (double)(cv.w / nk) * la3;
#pragma unroll
            for (int off = 1; off < 64; off <<= 1) part += __shfl_xor(part, off, 64);
            if (lane == 0) sc64[wid][c] = part;
        }
        __threadfence_block();
        double best64 = -1e300;
        for (int c = 0; c < nc; ++c) best64 = fmax(best64, sc64[wid][c]);
        int nrisk = 0;
        for (int c = 0; c < nc; ++c) if (sc64[wid][c] >= best64 - GTIE) ++nrisk;
        if (nrisk == 1) {
            idx = 0x7FFFFFFF; selcos = 0.f;
            for (int c = 0; c < nc; ++c)
                if (sc64[wid][c] >= best64 - GTIE) { idx = scand[wid][c]; selcos = (float)sc64[wid][c]; }
        } else {
            // rare: bit-exact np fp32 chains, one candidate per lane (R4 semantics)
            ull keyf = 0ull, keym = 0ull;
            if (lane < nc && sc64[wid][lane] >= best64 - GTIE) {
                int k = scand[wid][lane];
                const float* cr = cb + (size_t)k * DIM;
                const float* x = lat + (size_t)n * DIM;
                float nk = nrmc[k];
                float af = 0.f, am = 0.f;
                for (int d = 0; d < DIM; ++d) {
                    float la = x[d] / nx;
                    float cv = cr[d] / nk;
                    af = fmaf(la, cv, af);
                    am = __fadd_rn(am, __fmul_rn(la, cv));
                }
                float df = __fsub_rn(2.0f, __fmul_rn(2.0f, af));
                float dm = __fsub_rn(2.0f, __fmul_rn(2.0f, am));
                keyf = ((ull)(0xFFFFFFFFu - f2ord(df)) << 32) | (ull)(0xFFFFFFFFu - (unsigned)k);
                keym = ((ull)(0xFFFFFFFFu - f2ord(dm)) << 32) | (ull)(0xFFFFFFFFu - (unsigned)k);
            }
#pragma unroll
            for (int off = 1; off < 64; off <<= 1) {
                ull of = __shfl_xor(keyf, off, 64);
                ull om = __shfl_xor(keym, off, 64);
                keyf = of > keyf ? of : keyf;
                keym = om > keym ? om : keym;
            }
            int colf = (int)(0xFFFFFFFFu - (unsigned)(keyf & 0xFFFFFFFFull));
            int colm = (int)(0xFFFFFFFFu - (unsigned)(keym & 0xFFFFFFFFull));
            idx = colf < colm ? colf : colm;
            selcos = 0.f;
            for (int c = 0; c < nc; ++c)
                if (scand[wid][c] == idx) selcos = (float)sc64[wid][c];
        }
    }
    if (lane == 0) {
        fidx[n] = idx;
        outidx[n] = (float)idx;
        atomicAdd(&counts[idx], 1u);   // spread over 4096 addresses, ~2 hits each
        selw[n] = selcos;              // plain store, reduced in finalize
    }
}

// ---- gather quantized + mse partials (no atomics) ----
__global__ __launch_bounds__(256) void gather_out(const float* __restrict__ latent,
                                                  const float* __restrict__ codebook,
                                                  const int* __restrict__ fidx,
                                                  float* __restrict__ outq,
                                                  float* __restrict__ msew) {
    int t = threadIdx.x;
    int n0 = blockIdx.x * 16;
    float msePart = 0.f;
    for (int r = 0; r < 16; ++r) {
        int n = n0 + r;
        int idx = fidx[n];
        float q = codebook[(size_t)idx * DIM + t];
        float x = latent[(size_t)n * DIM + t];
        outq[(size_t)n * DIM + t] = q;
        float d = x - q;
        msePart = fmaf(d, d, msePart);
    }
    __shared__ float red[256];
    red[t] = msePart; __syncthreads();
    for (int s = 128; s > 0; s >>= 1) { if (t < s) red[t] += red[t + s]; __syncthreads(); }
    if (t == 0) msew[blockIdx.x] = red[0];
}

// ---- scalars: reduce all partial arrays ----
__global__ void finalize(const unsigned* __restrict__ counts,
                         const float* __restrict__ selw,
                         const float* __restrict__ msew,
                         const float* __restrict__ psumw,
                         const unsigned* __restrict__ pminw,
                         float* __restrict__ outs) {
    int t = threadIdx.x;
    __shared__ float red[256];
    // entropy over counts
    float h = 0.f;
    for (int k = t; k < KCB; k += 256) {
        float p = (float)counts[k] * (1.0f / (float)NTOK);
        h += p * logf(p + 1e-10f);
    }
    red[t] = h; __syncthreads();
    for (int s = 128; s > 0; s >>= 1) { if (t < s) red[t] += red[t + s]; __syncthreads(); }
    float entNeg = red[0];
    __syncthreads();
    // selected cosine sum
    float ssel = 0.f;
    for (int k = t; k < NTOK; k += 256) ssel += selw[k];
    red[t] = ssel; __syncthreads();
    for (int s = 128; s > 0; s >>= 1) { if (t < s) red[t] += red[t + s]; __syncthreads(); }
    float selSum = red[0];
    __syncthreads();
    // mse sum
    float sm = 0.f;
    for (int k = t; k < NGATB; k += 256) sm += msew[k];
    red[t] = sm; __syncthreads();
    for (int s = 128; s > 0; s >>= 1) { if (t < s) red[t] += red[t + s]; __syncthreads(); }
    float mseSum = red[0];
    __syncthreads();
    // pairwise sum
    float ps = 0.f;
    for (int k = t; k < NPAIRB; k += 256) ps += psumw[k];
    red[t] = ps; __syncthreads();
    for (int s = 128; s > 0; s >>= 1) { if (t < s) red[t] += red[t + s]; __syncthreads(); }
    float pairSum = red[0];
    __syncthreads();
    // pairwise min (as ordered u32)
    unsigned pm = 0xFFFFFFFFu;
    for (int k = t; k < NPAIRB; k += 256) pm = min(pm, pminw[k]);
    ((unsigned*)red)[t] = pm; __syncthreads();
    for (int s = 128; s > 0; s >>= 1) {
        if (t < s) ((unsigned*)red)[t] = min(((unsigned*)red)[t], ((unsigned*)red)[t + s]);
        __syncthreads();
    }
    unsigned pairMin = ((unsigned*)red)[0];
    if (t == 0) {
        float mse = mseSum / (float)(NTOK * DIM);
        outs[0] = 0.25f * mse;
        outs[1] = mse;
        outs[2] = expf(-entNeg);
        outs[3] = selSum / (float)NTOK;
        outs[4] = pairSum * 2.0f / ((float)KCB * (float)(KCB - 1));
        outs[5] = ord2f(pairMin);
    }
}

extern "C" void kernel_launch(void* const* d_in, const int* in_sizes, int n_in,
                              void* d_out, int out_size, void* d_ws, size_t ws_size,
                              hipStream_t stream) {
    const float* latent = (const float*)d_in[0];    // [8192,256]
    const float* codebook = (const float*)d_in[1];  // [4096,256]
    float* out = (float*)d_out;
    float* outq = out;
    float* outidx = out + (size_t)NTOK * DIM;
    float* outs = outidx + NTOK;

    ull* keysw = (ull*)d_ws;                                 // 128*8192 u64 = 8 MB
    ushort* latbf = (ushort*)(keysw + (size_t)NKROW * NTOK); // 4 MB
    ushort* cnbf = latbf + (size_t)NTOK * DIM;               // 2 MB
    ushort* cbbf = cnbf + (size_t)KCB * DIM;                 // 2 MB
    float* nrml = (float*)(cbbf + (size_t)KCB * DIM);        // 8192
    float* nrmc = nrml + NTOK;                               // 4096
    float* sq = nrmc + KCB;                                  // 4096
    int* fidx = (int*)(sq + KCB);                            // 8192
    unsigned* counts = (unsigned*)(fidx + NTOK);             // 4096
    float* selw = (float*)(counts + KCB);                    // 8192
    float* msew = selw + NTOK;                               // 512
    float* psumw = msew + NGATB;                             // 1024
    unsigned* pminw = (unsigned*)(psumw + NPAIRB);           // 1024

    hipLaunchKernelGGL(init_ws, dim3((KCB + 255) / 256), dim3(256), 0, stream, counts);
    hipLaunchKernelGGL(np_norms, dim3(NTOK / 256), dim3(256), 0, stream, latent, nrml, NTOK);
    hipLaunchKernelGGL(np_norms, dim3(KCB / 256), dim3(256), 0, stream, codebook, nrmc, KCB);
    hipLaunchKernelGGL(lat2bf, dim3(NTOK * DIM / 256), dim3(256), 0, stream, latent, latbf);
    hipLaunchKernelGGL(cb_apply, dim3(KCB), dim3(256), 0, stream, codebook, nrmc, cnbf, cbbf, sq);
    hipLaunchKernelGGL(scores_mfma, dim3(NCB, NTOK / 128), dim3(256), 0, stream, latbf, cnbf, keysw);
    hipLaunchKernelGGL(argmax_resolve, dim3(NTOK / 4), dim3(256), 0, stream,
                       latent, codebook, nrml, nrmc, keysw, outidx, fidx, counts, selw);
    hipLaunchKernelGGL(pairwise_mfma, dim3(NCB, NCB), dim3(256), 0, stream, cbbf, sq, psumw, pminw);
    hipLaunchKernelGGL(gather_out, dim3(NGATB), dim3(256), 0, stream, latent, codebook, fidx,
                       outq, msew);
    hipLaunchKernelGGL(finalize, dim3(1), dim3(256), 0, stream, counts, selw, msew, psumw, pminw, outs);
}

// Round 9
// 184.130 us; speedup vs baseline: 4.8009x; 1.1476x over previous
//
#include <hip/hip_runtime.h>
#include <hip/hip_bf16.h>
#include <math.h>

#define NTOK 8192
#define DIM 256
#define KCB 4096
#define NCB (KCB / 128)    // 32 col-blocks in score GEMM
#define NKEY 4             // top-4 kept per (row, col-block)
#define NKROW (NCB * NKEY) // 128 u32 keys per row
#define DELTA 0.08f        // candidate window, raw-dot units (~20 sigma of bf16 noise + quant)
#define GTIE 2e-6          // fp64 cosine gap below which we run the bit-exact np chain
#define MAXC 16
#define NPAIRB (NCB * (NCB + 1) / 2)  // 528 upper-triangle blocks
#define NGATB (NTOK / 16)  // 512 gather blocks

typedef unsigned long long ull;
typedef unsigned short ushort;
typedef __attribute__((ext_vector_type(8))) short shortx8;   // 8 bf16 (4 VGPRs)
typedef __attribute__((ext_vector_type(4))) float floatx4;
typedef const __attribute__((address_space(1))) void* gas_cp;
typedef __attribute__((address_space(3))) void* las_p;

// ---- float <-> order-preserving u32 ----
__device__ __forceinline__ unsigned f2ord(float f) {
    unsigned u = __float_as_uint(f);
    return (u & 0x80000000u) ? ~u : (u | 0x80000000u);
}
__device__ __forceinline__ float ord2f(unsigned u) {
    unsigned b = (u & 0x80000000u) ? (u & 0x7FFFFFFFu) : ~u;
    return __uint_as_float(b);
}
__device__ __forceinline__ ushort f2bf(float f) {   // RNE fp32->bf16
    unsigned u = __float_as_uint(f);
    unsigned r = u + 0x7FFFu + ((u >> 16) & 1u);
    return (ushort)(r >> 16);
}

// ---- shared-memory union: GEMM tiles alias the epilogue key store ----
union TileSmem {
    struct { ushort a[128][64]; ushort b[128][64]; } t;   // 32 KB
    unsigned keys[128][40];                               // 20 KB (stride 160 B, 16B-aligned)
};

// ---- async stage: 128 rows x 64 ushorts, XOR-swizzled chunks ----
__device__ __forceinline__ void stage_tile(const ushort* __restrict__ gbase,
                                           ushort (*lds)[64], int wave, int lane,
                                           int kk) {
    int p = lane & 7;
    int rsub = lane >> 3;
    int kc = p ^ (rsub & 7);
#pragma unroll
    for (int c = 0; c < 4; ++c) {
        int j = wave * 4 + c;
        const ushort* src = gbase + (size_t)(j * 8 + rsub) * DIM + kk + kc * 8;
        __builtin_amdgcn_global_load_lds((gas_cp)src, (las_p)&lds[j * 8][0], 16, 0, 0);
    }
}
__device__ __forceinline__ shortx8 frag_read(const ushort (*lds)[64], int row,
                                             int lc) {
    return *(const shortx8*)&lds[row][(lc ^ (row & 7)) * 8];
}

// ---- numpy fp32 pairwise-norm helper: combine 16 LDS accumulators exactly ----
__device__ __forceinline__ float np_combine(const float* racc) {
    float h0 = __fadd_rn(__fadd_rn(__fadd_rn(racc[0], racc[1]), __fadd_rn(racc[2], racc[3])),
                         __fadd_rn(__fadd_rn(racc[4], racc[5]), __fadd_rn(racc[6], racc[7])));
    float h1 = __fadd_rn(__fadd_rn(__fadd_rn(racc[8], racc[9]), __fadd_rn(racc[10], racc[11])),
                         __fadd_rn(__fadd_rn(racc[12], racc[13]), __fadd_rn(racc[14], racc[15])));
    float s = __fadd_rn(h0, h1);
    return fmaxf(sqrtf(s), 1e-12f);
}

// ---- latent prep: np norm (16 parallel accs, exact) + bf16 cvt + counts init ----
__global__ __launch_bounds__(256) void lat_prep(const float* __restrict__ lat,
                                                float* __restrict__ nrml,
                                                ushort* __restrict__ latbf,
                                                unsigned* __restrict__ counts) {
    int n = blockIdx.x, t = threadIdx.x;
    if (n < KCB / 256) counts[n * 256 + t] = 0u;
    const float* row = lat + (size_t)n * DIM;
    latbf[(size_t)n * DIM + t] = f2bf(row[t]);
    __shared__ float racc[16];
    if (t < 16) {
        int h = t >> 3, j = t & 7;
        const float* p = row + h * 128;
        float r = __fmul_rn(p[j], p[j]);
#pragma unroll 1
        for (int i = 8; i < 128; i += 8)
            r = __fadd_rn(r, __fmul_rn(p[i + j], p[i + j]));
        racc[t] = r;
    }
    __syncthreads();
    if (t == 0) nrml[n] = np_combine(racc);
}

// ---- codebook prep: np norm + fp64 sq + normalized/raw bf16 ----
__global__ __launch_bounds__(256) void cb_prep(const float* __restrict__ cb,
                                               float* __restrict__ nrmc,
                                               ushort* __restrict__ cnbf,
                                               ushort* __restrict__ cbbf,
                                               float* __restrict__ sq) {
    int n = blockIdx.x, t = threadIdx.x;
    __shared__ float racc[16];
    __shared__ double dacc[16];
    __shared__ float snrm;
    const float* row = cb + (size_t)n * DIM;
    if (t < 16) {
        int h = t >> 3, j = t & 7;
        const float* p = row + h * 128;
        float r = __fmul_rn(p[j], p[j]);
        double ds = 0.0;
#pragma unroll 1
        for (int i = 8; i < 128; i += 8)
            r = __fadd_rn(r, __fmul_rn(p[i + j], p[i + j]));
#pragma unroll 1
        for (int i = 0; i < 128; i += 8) { double v = (double)p[i + j]; ds += v * v; }
        racc[t] = r; dacc[t] = ds;
    }
    __syncthreads();
    if (t == 0) {
        float nr = np_combine(racc);
        snrm = nr; nrmc[n] = nr;
        double ds = 0.0;
        for (int i = 0; i < 16; ++i) ds += dacc[i];
        sq[n] = (float)ds;
    }
    __syncthreads();
    float c = row[t];
    cnbf[(size_t)n * DIM + t] = f2bf(c / snrm);
    cbbf[(size_t)n * DIM + t] = f2bf(c);
}

// ---- bf16 MFMA score GEMM + branchless u32-key top-4 per (row, col-block) ----
// key = (f2ord(v) & 0xFFFFF000) | (4095-col): 20-bit value (2e-3 granularity,
// fine vs DELTA=0.08 rescore window), 12-bit col, ties -> lowest col.
__global__ __launch_bounds__(256) void scores_mfma(const ushort* __restrict__ A,
                                                   const ushort* __restrict__ B,
                                                   unsigned* __restrict__ keysw) {
    __shared__ TileSmem sm;
    int tid = threadIdx.x;
    int wave = tid >> 6, lane = tid & 63;
    int quad = lane >> 4, l15 = lane & 15;
    int rowBase = blockIdx.y * 128, colBase = blockIdx.x * 128;
    int wrow = wave * 32;
    floatx4 acc[2][8];
#pragma unroll
    for (int m = 0; m < 2; ++m)
#pragma unroll
        for (int n = 0; n < 8; ++n) acc[m][n] = (floatx4){0.f, 0.f, 0.f, 0.f};
    const ushort* gA = A + (size_t)rowBase * DIM;
    const ushort* gB = B + (size_t)colBase * DIM;
#pragma unroll 1
    for (int kk = 0; kk < DIM; kk += 64) {
        __syncthreads();
        stage_tile(gA, sm.t.a, wave, lane, kk);
        stage_tile(gB, sm.t.b, wave, lane, kk);
        __syncthreads();
#pragma unroll
        for (int s = 0; s < 2; ++s) {
            shortx8 af[2], bf[8];
#pragma unroll
            for (int mt = 0; mt < 2; ++mt)
                af[mt] = frag_read(sm.t.a, wrow + mt * 16 + l15, s * 4 + quad);
#pragma unroll
            for (int nt = 0; nt < 8; ++nt)
                bf[nt] = frag_read(sm.t.b, nt * 16 + l15, s * 4 + quad);
#pragma unroll
            for (int mt = 0; mt < 2; ++mt)
#pragma unroll
                for (int nt = 0; nt < 8; ++nt)
                    acc[mt][nt] = __builtin_amdgcn_mfma_f32_16x16x32_bf16(
                        af[mt], bf[nt], acc[mt][nt], 0, 0, 0);
        }
    }
    __syncthreads();   // tiles dead; reuse LDS as keys
    unsigned colp[8];
#pragma unroll
    for (int nt = 0; nt < 8; ++nt)
        colp[nt] = 4095u - (unsigned)(colBase + nt * 16 + l15);
#pragma unroll
    for (int mt = 0; mt < 2; ++mt)
#pragma unroll
        for (int reg = 0; reg < 4; ++reg) {
            unsigned b1 = 0u, b2 = 0u;
#pragma unroll
            for (int nt = 0; nt < 8; ++nt) {
                unsigned key = (f2ord(acc[mt][nt][reg]) & 0xFFFFF000u) | colp[nt];
                unsigned lo = min(key, b1);
                b1 = max(key, b1);
                b2 = max(lo, b2);
            }
            int row = wrow + mt * 16 + quad * 4 + reg;
            uint2 kv; kv.x = b1; kv.y = b2;
            *(uint2*)&sm.keys[row][l15 * 2] = kv;
        }
    __syncthreads();
    if (tid < 128) {
        unsigned a0 = 0, a1 = 0, a2 = 0, a3 = 0;
#pragma unroll
        for (int j = 0; j < 8; ++j) {
            uint4 v4 = *(const uint4*)&sm.keys[tid][j * 4];
            unsigned vs[4] = {v4.x, v4.y, v4.z, v4.w};
#pragma unroll
            for (int q = 0; q < 4; ++q) {
                unsigned v = vs[q];
                unsigned n0 = min(v, a0); a0 = max(v, a0);
                unsigned n1 = min(n0, a1); a1 = max(n0, a1);
                unsigned n2 = min(n1, a2); a2 = max(n1, a2);
                a3 = max(n2, a3);
            }
        }
        size_t base = (size_t)(rowBase + tid) * NKROW + blockIdx.x * NKEY;
        uint4 o; o.x = a0; o.y = a1; o.z = a2; o.w = a3;
        *(uint4*)&keysw[base] = o;
    }
}

// ---- bf16 MFMA codebook pairwise: upper-triangle-only grid, per-block partials ----
__global__ __launch_bounds__(256) void pairwise_mfma(const ushort* __restrict__ C,
                                                     const float* __restrict__ sq,
                                                     float* __restrict__ psumw,
                                                     unsigned* __restrict__ pminw) {
    int tri = blockIdx.x;
    int a = (int)((sqrtf(8.f * tri + 1.f) - 1.f) * 0.5f);
    while ((a + 1) * (a + 2) / 2 <= tri) ++a;
    while (a * (a + 1) / 2 > tri) --a;
    int b = tri - a * (a + 1) / 2;   // a >= b
    int rowBase = b * 128, colBase = a * 128;
    __shared__ TileSmem sm;
    __shared__ float rs[256], rm[256];
    int tid = threadIdx.x;
    int wave = tid >> 6, lane = tid & 63;
    int quad = lane >> 4, l15 = lane & 15;
    int wrow = wave * 32;
    floatx4 acc[2][8];
#pragma unroll
    for (int m = 0; m < 2; ++m)
#pragma unroll
        for (int n = 0; n < 8; ++n) acc[m][n] = (floatx4){0.f, 0.f, 0.f, 0.f};
    const ushort* gA = C + (size_t)rowBase * DIM;
    const ushort* gB = C + (size_t)colBase * DIM;
#pragma unroll 1
    for (int kk = 0; kk < DIM; kk += 64) {
        __syncthreads();
        stage_tile(gA, sm.t.a, wave, lane, kk);
        stage_tile(gB, sm.t.b, wave, lane, kk);
        __syncthreads();
#pragma unroll
        for (int s = 0; s < 2; ++s) {
            shortx8 af[2], bf[8];
#pragma unroll
            for (int mt = 0; mt < 2; ++mt)
                af[mt] = frag_read(sm.t.a, wrow + mt * 16 + l15, s * 4 + quad);
#pragma unroll
            for (int nt = 0; nt < 8; ++nt)
                bf[nt] = frag_read(sm.t.b, nt * 16 + l15, s * 4 + quad);
#pragma unroll
            for (int mt = 0; mt < 2; ++mt)
#pragma unroll
                for (int nt = 0; nt < 8; ++nt)
                    acc[mt][nt] = __builtin_amdgcn_mfma_f32_16x16x32_bf16(
                        af[mt], bf[nt], acc[mt][nt], 0, 0, 0);
        }
    }
    float lsum = 0.f, lmin = INFINITY;
#pragma unroll
    for (int mt = 0; mt < 2; ++mt)
#pragma unroll
        for (int reg = 0; reg < 4; ++reg) {
            int i = rowBase + wrow + mt * 16 + quad * 4 + reg;
            float sqi = sq[i];
#pragma unroll
            for (int nt = 0; nt < 8; ++nt) {
                int j = colBase + nt * 16 + l15;
                float d2 = sqi + sq[j] - 2.0f * acc[mt][nt][reg];
                float d = sqrtf(fmaxf(d2, 0.0f));
                bool use = i < j;
                lsum += use ? d : 0.f;
                lmin = fminf(lmin, use ? d : INFINITY);
            }
        }
    rs[tid] = lsum; rm[tid] = lmin; __syncthreads();
    for (int s = 128; s > 0; s >>= 1) {
        if (tid < s) { rs[tid] += rs[tid + s]; rm[tid] = fminf(rm[tid], rm[tid + s]); }
        __syncthreads();
    }
    if (tid == 0) { psumw[tri] = rs[0]; pminw[tri] = f2ord(rm[0]); }
}

// ---- wave-per-row argmax resolve (u32 keys): no contended atomics ----
__global__ __launch_bounds__(256) void argmax_resolve(const float* __restrict__ lat,
                                                      const float* __restrict__ cb,
                                                      const float* __restrict__ nrml,
                                                      const float* __restrict__ nrmc,
                                                      const unsigned* __restrict__ keysw,
                                                      float* __restrict__ outidx,
                                                      int* __restrict__ fidx,
                                                      unsigned* __restrict__ counts,
                                                      float* __restrict__ selw) {
    __shared__ int scand[4][MAXC];
    __shared__ double sc64[4][MAXC];
    int wid = threadIdx.x >> 6, lane = threadIdx.x & 63;
    int n = blockIdx.x * 4 + wid;
    const unsigned* kr = keysw + (size_t)n * NKROW;
    uint2 kv = *(const uint2*)(kr + lane * 2);
    unsigned m = max(kv.x, kv.y);
#pragma unroll
    for (int off = 1; off < 64; off <<= 1) {
        unsigned o = __shfl_xor(m, off, 64);
        m = max(m, o);
    }
    float v1 = ord2f(m & 0xFFFFF000u);
    float thresh = v1 - DELTA;
    bool p0 = ord2f(kv.x & 0xFFFFF000u) >= thresh;
    bool p1 = ord2f(kv.y & 0xFFFFF000u) >= thresh;
    ull b0 = __ballot(p0), b1 = __ballot(p1);
    int below0 = __builtin_amdgcn_mbcnt_hi((unsigned)(b0 >> 32),
                 __builtin_amdgcn_mbcnt_lo((unsigned)b0, 0));
    int below1 = __builtin_amdgcn_mbcnt_hi((unsigned)(b1 >> 32),
                 __builtin_amdgcn_mbcnt_lo((unsigned)b1, 0));
    int base1 = __popcll(b0);
    int nc = base1 + __popcll(b1);
    if (p0 && below0 < MAXC)
        scand[wid][below0] = 4095 - (int)(kv.x & 0xFFFu);
    if (p1 && base1 + below1 < MAXC)
        scand[wid][base1 + below1] = 4095 - (int)(kv.y & 0xFFFu);
    nc = nc < MAXC ? nc : MAXC;
    __threadfence_block();
    float nx = nrml[n];
    int idx; float selcos;
    if (nc <= 1) {
        idx = 4095 - (int)(m & 0xFFFu);
        selcos = v1 / nx;
    } else {
        int d0 = lane * 4;
        float4 xv = *(const float4*)(lat + (size_t)n * DIM + d0);
        float la0 = xv.x / nx, la1 = xv.y / nx, la2 = xv.z / nx, la3 = xv.w / nx;
        for (int c = 0; c < nc; ++c) {
            int k = scand[wid][c];
            float nk = nrmc[k];
            float4 cv = *(const float4*)(cb + (size_t)k * DIM + d0);
            double part = (double)(cv.x / nk) * la0 + (double)(cv.y / nk) * la1 +
                          (double)(cv.z / nk) * la2 + (double)(cv.w / nk) * la3;
#pragma unroll
            for (int off = 1; off < 64; off <<= 1) part += __shfl_xor(part, off, 64);
            if (lane == 0) sc64[wid][c] = part;
        }
        __threadfence_block();
        double best64 = -1e300;
        for (int c = 0; c < nc; ++c) best64 = fmax(best64, sc64[wid][c]);
        int nrisk = 0;
        for (int c = 0; c < nc; ++c) if (sc64[wid][c] >= best64 - GTIE) ++nrisk;
        if (nrisk == 1) {
            idx = 0x7FFFFFFF; selcos = 0.f;
            for (int c = 0; c < nc; ++c)
                if (sc64[wid][c] >= best64 - GTIE) { idx = scand[wid][c]; selcos = (float)sc64[wid][c]; }
        } else {
            // rare: bit-exact np fp32 chains, one candidate per lane (R4 semantics)
            ull keyf = 0ull, keym = 0ull;
            if (lane < nc && sc64[wid][lane] >= best64 - GTIE) {
                int k = scand[wid][lane];
                const float* cr = cb + (size_t)k * DIM;
                const float* x = lat + (size_t)n * DIM;
                float nk = nrmc[k];
                float af = 0.f, am = 0.f;
                for (int d = 0; d < DIM; ++d) {
                    float la = x[d] / nx;
                    float cv = cr[d] / nk;
                    af = fmaf(la, cv, af);
                    am = __fadd_rn(am, __fmul_rn(la, cv));
                }
                float df = __fsub_rn(2.0f, __fmul_rn(2.0f, af));
                float dm = __fsub_rn(2.0f, __fmul_rn(2.0f, am));
                keyf = ((ull)(0xFFFFFFFFu - f2ord(df)) << 32) | (ull)(0xFFFFFFFFu - (unsigned)k);
                keym = ((ull)(0xFFFFFFFFu - f2ord(dm)) << 32) | (ull)(0xFFFFFFFFu - (unsigned)k);
            }
#pragma unroll
            for (int off = 1; off < 64; off <<= 1) {
                ull of = __shfl_xor(keyf, off, 64);
                ull om = __shfl_xor(keym, off, 64);
                keyf = of > keyf ? of : keyf;
                keym = om > keym ? om : keym;
            }
            int colf = (int)(0xFFFFFFFFu - (unsigned)(keyf & 0xFFFFFFFFull));
            int colm = (int)(0xFFFFFFFFu - (unsigned)(keym & 0xFFFFFFFFull));
            idx = colf < colm ? colf : colm;
            selcos = 0.f;
            for (int c = 0; c < nc; ++c)
                if (scand[wid][c] == idx) selcos = (float)sc64[wid][c];
        }
    }
    if (lane == 0) {
        fidx[n] = idx;
        outidx[n] = (float)idx;
        atomicAdd(&counts[idx], 1u);   // spread over 4096 addresses
        selw[n] = selcos;
    }
}

// ---- gather quantized + mse partials (no atomics) ----
__global__ __launch_bounds__(256) void gather_out(const float* __restrict__ latent,
                                                  const float* __restrict__ codebook,
                                                  const int* __restrict__ fidx,
                                                  float* __restrict__ outq,
                                                  float* __restrict__ msew) {
    int t = threadIdx.x;
    int n0 = blockIdx.x * 16;
    float msePart = 0.f;
    for (int r = 0; r < 16; ++r) {
        int n = n0 + r;
        int idx = fidx[n];
        float q = codebook[(size_t)idx * DIM + t];
        float x = latent[(size_t)n * DIM + t];
        outq[(size_t)n * DIM + t] = q;
        float d = x - q;
        msePart = fmaf(d, d, msePart);
    }
    __shared__ float red[256];
    red[t] = msePart; __syncthreads();
    for (int s = 128; s > 0; s >>= 1) { if (t < s) red[t] += red[t + s]; __syncthreads(); }
    if (t == 0) msew[blockIdx.x] = red[0];
}

// ---- scalars: reduce all partial arrays ----
__global__ void finalize(const unsigned* __restrict__ counts,
                         const float* __restrict__ selw,
                         const float* __restrict__ msew,
                         const float* __restrict__ psumw,
                         const unsigned* __restrict__ pminw,
                         float* __restrict__ outs) {
    int t = threadIdx.x;
    __shared__ float red[256];
    float h = 0.f;
    for (int k = t; k < KCB; k += 256) {
        float p = (float)counts[k] * (1.0f / (float)NTOK);
        h += p * logf(p + 1e-10f);
    }
    red[t] = h; __syncthreads();
    for (int s = 128; s > 0; s >>= 1) { if (t < s) red[t] += red[t + s]; __syncthreads(); }
    float entNeg = red[0];
    __syncthreads();
    float ssel = 0.f;
    for (int k = t; k < NTOK; k += 256) ssel += selw[k];
    red[t] = ssel; __syncthreads();
    for (int s = 128; s > 0; s >>= 1) { if (t < s) red[t] += red[t + s]; __syncthreads(); }
    float selSum = red[0];
    __syncthreads();
    float sm = 0.f;
    for (int k = t; k < NGATB; k += 256) sm += msew[k];
    red[t] = sm; __syncthreads();
    for (int s = 128; s > 0; s >>= 1) { if (t < s) red[t] += red[t + s]; __syncthreads(); }
    float mseSum = red[0];
    __syncthreads();
    float ps = 0.f;
    for (int k = t; k < NPAIRB; k += 256) ps += psumw[k];
    red[t] = ps; __syncthreads();
    for (int s = 128; s > 0; s >>= 1) { if (t < s) red[t] += red[t + s]; __syncthreads(); }
    float pairSum = red[0];
    __syncthreads();
    unsigned pm = 0xFFFFFFFFu;
    for (int k = t; k < NPAIRB; k += 256) pm = min(pm, pminw[k]);
    ((unsigned*)red)[t] = pm; __syncthreads();
    for (int s = 128; s > 0; s >>= 1) {
        if (t < s) ((unsigned*)red)[t] = min(((unsigned*)red)[t], ((unsigned*)red)[t + s]);
        __syncthreads();
    }
    unsigned pairMin = ((unsigned*)red)[0];
    if (t == 0) {
        float mse = mseSum / (float)(NTOK * DIM);
        outs[0] = 0.25f * mse;
        outs[1] = mse;
        outs[2] = expf(-entNeg);
        outs[3] = selSum / (float)NTOK;
        outs[4] = pairSum * 2.0f / ((float)KCB * (float)(KCB - 1));
        outs[5] = ord2f(pairMin);
    }
}

extern "C" void kernel_launch(void* const* d_in, const int* in_sizes, int n_in,
                              void* d_out, int out_size, void* d_ws, size_t ws_size,
                              hipStream_t stream) {
    const float* latent = (const float*)d_in[0];    // [8192,256]
    const float* codebook = (const float*)d_in[1];  // [4096,256]
    float* out = (float*)d_out;
    float* outq = out;
    float* outidx = out + (size_t)NTOK * DIM;
    float* outs = outidx + NTOK;

    unsigned* keysw = (unsigned*)d_ws;                        // 128*8192 u32 = 4 MB
    ushort* latbf = (ushort*)(keysw + (size_t)NKROW * NTOK);  // 4 MB
    ushort* cnbf = latbf + (size_t)NTOK * DIM;                // 2 MB
    ushort* cbbf = cnbf + (size_t)KCB * DIM;                  // 2 MB
    float* nrml = (float*)(cbbf + (size_t)KCB * DIM);         // 8192
    float* nrmc = nrml + NTOK;                                // 4096
    float* sq = nrmc + KCB;                                   // 4096
    int* fidx = (int*)(sq + KCB);                             // 8192
    unsigned* counts = (unsigned*)(fidx + NTOK);              // 4096
    float* selw = (float*)(counts + KCB);                     // 8192
    float* msew = selw + NTOK;                                // 512
    float* psumw = msew + NGATB;                              // 528
    unsigned* pminw = (unsigned*)(psumw + NPAIRB);            // 528

    hipLaunchKernelGGL(lat_prep, dim3(NTOK), dim3(256), 0, stream, latent, nrml, latbf, counts);
    hipLaunchKernelGGL(cb_prep, dim3(KCB), dim3(256), 0, stream, codebook, nrmc, cnbf, cbbf, sq);
    hipLaunchKernelGGL(scores_mfma, dim3(NCB, NTOK / 128), dim3(256), 0, stream, latbf, cnbf, keysw);
    hipLaunchKernelGGL(argmax_resolve, dim3(NTOK / 4), dim3(256), 0, stream,
                       latent, codebook, nrml, nrmc, keysw, outidx, fidx, counts, selw);
    hipLaunchKernelGGL(pairwise_mfma, dim3(NPAIRB), dim3(256), 0, stream, cbbf, sq, psumw, pminw);
    hipLaunchKernelGGL(gather_out, dim3(NGATB), dim3(256), 0, stream, latent, codebook, fidx,
                       outq, msew);
    hipLaunchKernelGGL(finalize, dim3(1), dim3(256), 0, stream, counts, selw, msew, psumw, pminw, outs);
}